// Round 15
// baseline (217.965 us; speedup 1.0000x reference)
//
#include <hip/hip_runtime.h>
#include <math.h>

namespace {

constexpr int NF   = 256;   // n_feature / tokens
constexpr int EH   = 128;   // embedder hidden
constexpr int E    = 64;    // embedded dim
constexpr int H    = 64;    // lstm size
constexpr int SHD  = 256;   // shared hidden
constexpr int SD   = 128;   // shared dim
constexpr int NA   = 257;   // n_action
constexpr int NSHUF = 4;

__device__ __forceinline__ float fsig(float x) {
  return 1.f / (1.f + __expf(-x));
}
__device__ __forceinline__ float ftanh(float x) {
  return 1.f - 2.f / (__expf(2.f * x) + 1.f);
}

// TWO WAVES PER ROW (r14's zero-barrier wave kernel, split 2x for occupancy):
// grid gives only 8 waves/CU at 1 wave/row (22% occupancy, r14); 2 waves/row
// -> 16/CU and halves each wave's critical path. Barriers sync only 2 waves.
// Factored attention (r11-r14-verified): logits = h.(We2 qt) (const cancels);
// attended = (sum w h)@We2 + be2; h recomputed from We1 on the fly.
// Token->group map tok = 8*i + gq balances 8 sixteen-lane groups for any L.
// Allocator model: (128,2) -> cap 256 -> lands <=128 VGPR (4 waves/SIMD tier).
__global__ __launch_bounds__(128, 2)
void seqnet(
    const float* __restrict__ state, const int* __restrict__ acquired,
    const float* __restrict__ We1, const float* __restrict__ be1,
    const float* __restrict__ We2, const float* __restrict__ be2,
    const float* __restrict__ Wih, const float* __restrict__ Whh,
    const float* __restrict__ bih, const float* __restrict__ bhh,
    const float* __restrict__ Ws1, const float* __restrict__ bs1,
    const float* __restrict__ Ws2, const float* __restrict__ bs2,
    const float* __restrict__ Wp1, const float* __restrict__ bp1,
    const float* __restrict__ Wp2, const float* __restrict__ bp2,
    const float* __restrict__ Wv1, const float* __restrict__ bv1,
    const float* __restrict__ Wv2, const float* __restrict__ bv2,
    float* __restrict__ out)
{
  const int row = blockIdx.x;
  const int t   = threadIdx.x;    // 0..127
  const int l   = t & 63;
  const int wv  = t >> 6;         // wave 0/1
  const int gq  = t >> 4;         // token group 0..7
  const int sub = t & 15;         // k-slice owner within group
  const int kbase = sub * 8;      // owns k = kbase..kbase+7

  __shared__ int   id_s[NF];
  __shared__ __align__(16) float val_s[NF];
  __shared__ __align__(16) float w_s[NF];
  __shared__ __align__(16) float rv_s[EH];
  __shared__ __align__(16) float pu_s[2][EH];   // per-wave u partials
  __shared__ __align__(16) float red_s[128];
  __shared__ __align__(16) float att_s[E];
  __shared__ __align__(16) float qt_s[H];
  __shared__ __align__(16) float gates_s[256];
  __shared__ __align__(16) float t1_s[SHD];
  __shared__ __align__(16) float sh_s[SD];
  __shared__ __align__(16) float a1_s[SD];
  __shared__ __align__(16) float v1_s[SD];
  __shared__ float wred2[2][3];   // per-wave {adv256, v, advsum}
  __shared__ int   L_s;

  // ---------------- phase 0: closed-form "argsort" (wave 0 only) ----------
  if (wv == 0) {
    const int* __restrict__ arow = acquired + row * NF;
    #pragma unroll
    for (int j = 0; j < 4; ++j) { id_s[l + 64 * j] = 0; val_s[l + 64 * j] = 0.f; }
    const int a0v = (arow[l]       != 0); const unsigned long long m0 = __ballot(a0v);
    const int a1v = (arow[64 + l]  != 0); const unsigned long long m1 = __ballot(a1v);
    const int a2v = (arow[128 + l] != 0); const unsigned long long m2 = __ballot(a2v);
    const int a3v = (arow[192 + l] != 0); const unsigned long long m3 = __ballot(a3v);
    const int pc0 = __popcll(m0), pc1 = __popcll(m1);
    const int pc2 = __popcll(m2), pc3 = __popcll(m3);
    const int suf1 = pc1 + pc2 + pc3, suf2 = pc2 + pc3, suf3 = pc3;
    if (a0v) { const int r = (int)__popcll((m0 >> l) >> 1) + suf1;
      id_s[r] = l + 1;       val_s[r] = state[row * NF + l]; }
    if (a1v) { const int r = (int)__popcll((m1 >> l) >> 1) + suf2;
      id_s[r] = 64 + l + 1;  val_s[r] = state[row * NF + 64 + l]; }
    if (a2v) { const int r = (int)__popcll((m2 >> l) >> 1) + suf3;
      id_s[r] = 128 + l + 1; val_s[r] = state[row * NF + 128 + l]; }
    if (a3v) { const int r = (int)__popcll((m3 >> l) >> 1);
      id_s[r] = 192 + l + 1; val_s[r] = state[row * NF + 192 + l]; }
    if (l == 0) L_s = pc0 + pc1 + pc2 + pc3;
  }
  __syncthreads();
  const int L = L_s;

  float ct_r = 0.f;   // LSTM cell state, live on wave-0 lanes only

  // hoisted per-lane h-recompute constants for k-slice [kbase, kbase+8)
  const float4 z0 = *(const float4*)(We1 + kbase);        // row 0 (val weight)
  const float4 z1 = *(const float4*)(We1 + kbase + 4);
  const float4 c0 = *(const float4*)(be1 + kbase);
  const float4 c1 = *(const float4*)(be1 + kbase + 4);

  if (L > 0) {
    const float invL = 1.f / (float)L;
    const int ntok = (L > gq) ? ((L - gq + 7) >> 3) : 0;   // group trip count
    for (int it = 0; it < NSHUF; ++it) {
      if (it == 0) {
        // qt == 0 -> uniform softmax over first L tokens
        w_s[t]       = (t < L)       ? invL : 0.f;
        w_s[128 + t] = (128 + t < L) ? invL : 0.f;
        __syncthreads();
      } else {
        // rv[t] = We2 row t . qt (qt broadcast from LDS, float4)
        {
          const float4* __restrict__ wr = (const float4*)(We2 + t * E);
          float x0 = 0.f, x1 = 0.f, x2 = 0.f, x3 = 0.f;
          #pragma unroll
          for (int j = 0; j < 16; ++j) {
            const float4 w4 = wr[j];
            const float4 q4 = *(const float4*)(qt_s + 4 * j);
            x0 = fmaf(w4.x, q4.x, x0); x1 = fmaf(w4.y, q4.y, x1);
            x2 = fmaf(w4.z, q4.z, x2); x3 = fmaf(w4.w, q4.w, x3);
          }
          rv_s[t] = (x0 + x1) + (x2 + x3);
        }
        __syncthreads();
        const float4 ra = *(const float4*)(rv_s + kbase);
        const float4 rb = *(const float4*)(rv_s + kbase + 4);
        // logits: group gq, token 8i+gq; 16 lanes cover k; 4-step butterfly
        for (int i = 0; i < ntok; ++i) {
          const int tok = 8 * i + gq;
          const int   idt = id_s[tok];
          const float vt  = val_s[tok];
          const float4* __restrict__ gr = (const float4*)(We1 + idt * EH + kbase);
          const float4 ga = gr[0], gb = gr[1];
          float h, p;
          h = fmaxf(fmaf(vt, z0.x, ga.x) + c0.x, 0.f); p = h * ra.x;
          h = fmaxf(fmaf(vt, z0.y, ga.y) + c0.y, 0.f); p = fmaf(h, ra.y, p);
          h = fmaxf(fmaf(vt, z0.z, ga.z) + c0.z, 0.f); p = fmaf(h, ra.z, p);
          h = fmaxf(fmaf(vt, z0.w, ga.w) + c0.w, 0.f); p = fmaf(h, ra.w, p);
          h = fmaxf(fmaf(vt, z1.x, gb.x) + c1.x, 0.f); p = fmaf(h, rb.x, p);
          h = fmaxf(fmaf(vt, z1.y, gb.y) + c1.y, 0.f); p = fmaf(h, rb.y, p);
          h = fmaxf(fmaf(vt, z1.z, gb.z) + c1.z, 0.f); p = fmaf(h, rb.z, p);
          h = fmaxf(fmaf(vt, z1.w, gb.w) + c1.w, 0.f); p = fmaf(h, rb.w, p);
          p += __shfl_xor(p, 1); p += __shfl_xor(p, 2);
          p += __shfl_xor(p, 4); p += __shfl_xor(p, 8);
          if (sub == 0) w_s[tok] = p;
        }
        __syncthreads();
        // softmax stats redundant per wave; each thread writes 2 of 256 slots
        float x0 = (l < L)       ? w_s[l]       : -1e30f;
        float x1 = (64 + l < L)  ? w_s[64 + l]  : -1e30f;
        float x2 = (128 + l < L) ? w_s[128 + l] : -1e30f;
        float x3 = (192 + l < L) ? w_s[192 + l] : -1e30f;
        float mx = fmaxf(fmaxf(x0, x1), fmaxf(x2, x3));
        #pragma unroll
        for (int d = 32; d > 0; d >>= 1) mx = fmaxf(mx, __shfl_xor(mx, d));
        const float e0 = (l < L)       ? __expf(x0 - mx) : 0.f;
        const float e1 = (64 + l < L)  ? __expf(x1 - mx) : 0.f;
        const float e2 = (128 + l < L) ? __expf(x2 - mx) : 0.f;
        const float e3 = (192 + l < L) ? __expf(x3 - mx) : 0.f;
        float s = (e0 + e1) + (e2 + e3);
        #pragma unroll
        for (int d = 32; d > 0; d >>= 1) s += __shfl_xor(s, d);
        const float inv = 1.f / s;
        if (wv == 0) { w_s[l]      = e0 * inv; w_s[128 + l] = e2 * inv; }
        else         { w_s[64 + l] = e1 * inv; w_s[192 + l] = e3 * inv; }
        __syncthreads();
      }

      // u[k] = sum_tok w*h : per-lane 8-k accum over group's tokens
      float4 ua{0, 0, 0, 0}, ub{0, 0, 0, 0};
      for (int i = 0; i < ntok; ++i) {
        const int tok = 8 * i + gq;
        const int   idt = id_s[tok];
        const float vt  = val_s[tok];
        const float wt  = w_s[tok];
        const float4* __restrict__ gr = (const float4*)(We1 + idt * EH + kbase);
        const float4 ga = gr[0], gb = gr[1];
        float h;
        h = fmaxf(fmaf(vt, z0.x, ga.x) + c0.x, 0.f); ua.x = fmaf(wt, h, ua.x);
        h = fmaxf(fmaf(vt, z0.y, ga.y) + c0.y, 0.f); ua.y = fmaf(wt, h, ua.y);
        h = fmaxf(fmaf(vt, z0.z, ga.z) + c0.z, 0.f); ua.z = fmaf(wt, h, ua.z);
        h = fmaxf(fmaf(vt, z0.w, ga.w) + c0.w, 0.f); ua.w = fmaf(wt, h, ua.w);
        h = fmaxf(fmaf(vt, z1.x, gb.x) + c1.x, 0.f); ub.x = fmaf(wt, h, ub.x);
        h = fmaxf(fmaf(vt, z1.y, gb.y) + c1.y, 0.f); ub.y = fmaf(wt, h, ub.y);
        h = fmaxf(fmaf(vt, z1.z, gb.z) + c1.z, 0.f); ub.z = fmaf(wt, h, ub.z);
        h = fmaxf(fmaf(vt, z1.w, gb.w) + c1.w, 0.f); ub.w = fmaf(wt, h, ub.w);
      }
      #pragma unroll
      for (int d = 16; d <= 32; d <<= 1) {   // reduce this wave's 4 groups
        ua.x += __shfl_xor(ua.x, d); ua.y += __shfl_xor(ua.y, d);
        ua.z += __shfl_xor(ua.z, d); ua.w += __shfl_xor(ua.w, d);
        ub.x += __shfl_xor(ub.x, d); ub.y += __shfl_xor(ub.y, d);
        ub.z += __shfl_xor(ub.z, d); ub.w += __shfl_xor(ub.w, d);
      }
      if (l < 16) {
        *(float4*)(pu_s[wv] + l * 8)     = ua;
        *(float4*)(pu_s[wv] + l * 8 + 4) = ub;
      }
      __syncthreads();

      // attended[c] = sum_k (pu0[k]+pu1[k]) * We2[k][c]; k split by wave
      {
        const int c  = l;
        const int k0 = wv * 64;
        float b0 = 0.f, b1 = 0.f, b2 = 0.f, b3 = 0.f;
        #pragma unroll 2
        for (int k = 0; k < 64; k += 4) {
          const int kk = k0 + k;
          const float u0 = pu_s[0][kk]     + pu_s[1][kk];
          const float u1 = pu_s[0][kk + 1] + pu_s[1][kk + 1];
          const float u2 = pu_s[0][kk + 2] + pu_s[1][kk + 2];
          const float u3 = pu_s[0][kk + 3] + pu_s[1][kk + 3];
          b0 = fmaf(u0, We2[(kk)     * E + c], b0);
          b1 = fmaf(u1, We2[(kk + 1) * E + c], b1);
          b2 = fmaf(u2, We2[(kk + 2) * E + c], b2);
          b3 = fmaf(u3, We2[(kk + 3) * E + c], b3);
        }
        red_s[t] = (b0 + b1) + (b2 + b3);
      }
      __syncthreads();
      if (t < 64) att_s[t] = red_s[t] + red_s[64 + t] + be2[t];
      __syncthreads();

      // gates: thread t owns cols t and 128+t
      {
        float ga_ = 0.f, gb_ = 0.f;
        #pragma unroll 2
        for (int e = 0; e < E; ++e) {
          const float av = att_s[e];
          const float* __restrict__ wc = Wih + e * 256;
          ga_ = fmaf(av, wc[t],       ga_);
          gb_ = fmaf(av, wc[128 + t], gb_);
        }
        if (it > 0) {
          #pragma unroll 2
          for (int e = 0; e < E; ++e) {
            const float qv = qt_s[e];
            const float* __restrict__ wc = Whh + e * 256;
            ga_ = fmaf(qv, wc[t],       ga_);
            gb_ = fmaf(qv, wc[128 + t], gb_);
          }
        }
        gates_s[t]       = ga_ + bih[t]       + bhh[t];
        gates_s[128 + t] = gb_ + bih[128 + t] + bhh[128 + t];
      }
      __syncthreads();
      if (t < 64) {
        const float ig = gates_s[t];
        const float fg = gates_s[64 + t];
        const float gg = gates_s[128 + t];
        const float og = gates_s[192 + t];
        ct_r = fsig(fg) * ct_r + fsig(ig) * ftanh(gg);
        qt_s[t] = fsig(og) * ftanh(ct_r);
      }
      __syncthreads();
    }
  } else {
    if (t < 64) { att_s[t] = 0.f; qt_s[t] = 0.f; }   // reference zeroes encoded
    __syncthreads();
  }

  // ---------------- phase 3: DuelingNet (128 threads, coalesced) ----------
  {  // t1 cols t, 128+t; k over att(64) then qt(64)
    float p0 = 0.f, p1 = 0.f;
    #pragma unroll 2
    for (int k = 0; k < 64; ++k) {
      const float ev = att_s[k];
      const float* __restrict__ wr = Ws1 + k * SHD;
      p0 = fmaf(ev, wr[t],       p0);
      p1 = fmaf(ev, wr[128 + t], p1);
    }
    #pragma unroll 2
    for (int k = 0; k < 64; ++k) {
      const float qv = qt_s[k];
      const float* __restrict__ wr = Ws1 + (64 + k) * SHD;
      p0 = fmaf(qv, wr[t],       p0);
      p1 = fmaf(qv, wr[128 + t], p1);
    }
    t1_s[t]       = fmaxf(p0 + bs1[t],       0.f);
    t1_s[128 + t] = fmaxf(p1 + bs1[128 + t], 0.f);
  }
  __syncthreads();
  {  // sh col t
    float s0 = 0.f, s1 = 0.f;
    #pragma unroll 2
    for (int k = 0; k < SHD; k += 2) {
      s0 = fmaf(t1_s[k],     Ws2[(k)     * SD + t], s0);
      s1 = fmaf(t1_s[k + 1], Ws2[(k + 1) * SD + t], s1);
    }
    sh_s[t] = fmaxf(s0 + s1 + bs2[t], 0.f);
  }
  __syncthreads();
  {  // a1[t], v1[t]
    float p = 0.f, q = 0.f;
    #pragma unroll 2
    for (int k = 0; k < SD; ++k) {
      const float sv = sh_s[k];
      p = fmaf(sv, Wp1[k * SD + t], p);
      q = fmaf(sv, Wv1[k * SD + t], q);
    }
    a1_s[t] = fmaxf(p + bp1[t], 0.f);
    v1_s[t] = fmaxf(q + bv1[t], 0.f);
  }
  __syncthreads();
  // adv cols t, 128+t; col 256 + v + mean via block reduction
  float a0 = 0.f, a1v = 0.f;
  #pragma unroll 2
  for (int k = 0; k < SD; ++k) {
    const float av = a1_s[k];
    const float* __restrict__ wr = Wp2 + k * NA;
    a0  = fmaf(av, wr[t],       a0);
    a1v = fmaf(av, wr[128 + t], a1v);
  }
  a0 += bp2[t]; a1v += bp2[128 + t];
  float c4 = a1_s[t] * Wp2[t * NA + 256];     // col-256 partial (k = t)
  float vv = v1_s[t] * Wv2[t];                // v partial (k = t)
  float ss = a0 + a1v;                        // adv-sum partial (cols t,128+t)
  #pragma unroll
  for (int d = 32; d > 0; d >>= 1) {
    c4 += __shfl_xor(c4, d);
    vv += __shfl_xor(vv, d);
    ss += __shfl_xor(ss, d);
  }
  if (l == 0) { wred2[wv][0] = c4; wred2[wv][1] = vv; wred2[wv][2] = ss; }
  __syncthreads();
  const float adv4 = wred2[0][0] + wred2[1][0] + bp2[256];
  const float v    = wred2[0][1] + wred2[1][1] + bv2[0];
  const float mean = (wred2[0][2] + wred2[1][2] + adv4) * (1.f / (float)NA);
  const float base = v - mean;
  float* __restrict__ orow = out + row * NA;
  orow[t]       = base + a0;
  orow[128 + t] = base + a1v;
  if (t == 0) orow[256] = base + adv4;
}

}  // namespace

extern "C" void kernel_launch(void* const* d_in, const int* in_sizes, int n_in,
                              void* d_out, int out_size, void* d_ws, size_t ws_size,
                              hipStream_t stream) {
  const float* state    = (const float*)d_in[0];
  const int*   acquired = (const int*)d_in[1];
  const float* We1 = (const float*)d_in[2];
  const float* be1 = (const float*)d_in[3];
  const float* We2 = (const float*)d_in[4];
  const float* be2 = (const float*)d_in[5];
  const float* Wih = (const float*)d_in[6];
  const float* Whh = (const float*)d_in[7];
  const float* bih = (const float*)d_in[8];
  const float* bhh = (const float*)d_in[9];
  const float* Ws1 = (const float*)d_in[10];
  const float* bs1 = (const float*)d_in[11];
  const float* Ws2 = (const float*)d_in[12];
  const float* bs2 = (const float*)d_in[13];
  const float* Wp1 = (const float*)d_in[14];
  const float* bp1 = (const float*)d_in[15];
  const float* Wp2 = (const float*)d_in[16];
  const float* bp2 = (const float*)d_in[17];
  const float* Wv1 = (const float*)d_in[18];
  const float* bv1 = (const float*)d_in[19];
  const float* Wv2 = (const float*)d_in[20];
  const float* bv2 = (const float*)d_in[21];
  float* out = (float*)d_out;

  const int Bn = in_sizes[0] / NF;   // 2048 rows; two waves per row
  hipLaunchKernelGGL(seqnet, dim3(Bn), dim3(128), 0, stream,
                     state, acquired, We1, be1, We2, be2, Wih, Whh, bih, bhh,
                     Ws1, bs1, Ws2, bs2, Wp1, bp1, Wp2, bp2, Wv1, bv1, Wv2, bv2,
                     out);
}

// Round 16
// 158.108 us; speedup vs baseline: 1.3786x; 1.3786x over previous
//
#include <hip/hip_runtime.h>
#include <math.h>

namespace {

constexpr int NF   = 256;   // n_feature / tokens
constexpr int NFP  = NF + 8;// padded (prefetch overrun, zero-filled)
constexpr int EH   = 128;   // embedder hidden
constexpr int E    = 64;    // embedded dim
constexpr int H    = 64;    // lstm size
constexpr int SHD  = 256;   // shared hidden
constexpr int SD   = 128;   // shared dim
constexpr int NA   = 257;   // n_action
constexpr int NSHUF = 4;

__device__ __forceinline__ float fsig(float x) {
  return 1.f / (1.f + __expf(-x));
}
__device__ __forceinline__ float ftanh(float x) {
  return 1.f - 2.f / (__expf(2.f * x) + 1.f);
}

// ONE WAVE PER ROW, ZERO BARRIERS (r14 structure, 174us) + software-pipelined
// token loops: dual-stream (2 tokens/iter) + 1-deep prefetch of meta and We1
// rows -> ~4 loads in flight vs 1 (r14 was latency-bound: VALUBusy 21%).
// Factored attention (r11-r15-verified): logits = h.(We2 qt) (const cancels);
// attended = (sum w h)@We2 + be2; h recomputed from We1 on the fly.
__global__ __launch_bounds__(64)
void seqnet(
    const float* __restrict__ state, const int* __restrict__ acquired,
    const float* __restrict__ We1, const float* __restrict__ be1,
    const float* __restrict__ We2, const float* __restrict__ be2,
    const float* __restrict__ Wih, const float* __restrict__ Whh,
    const float* __restrict__ bih, const float* __restrict__ bhh,
    const float* __restrict__ Ws1, const float* __restrict__ bs1,
    const float* __restrict__ Ws2, const float* __restrict__ bs2,
    const float* __restrict__ Wp1, const float* __restrict__ bp1,
    const float* __restrict__ Wp2, const float* __restrict__ bp2,
    const float* __restrict__ Wv1, const float* __restrict__ bv1,
    const float* __restrict__ Wv2, const float* __restrict__ bv2,
    float* __restrict__ out)
{
  const int row = blockIdx.x;
  const int l   = threadIdx.x;    // 0..63 (one wave)
  const int g   = l >> 4;         // token group 0..3
  const int sub = l & 15;         // k-slice owner within group
  const int kbase = sub * 8;      // owns k = kbase..kbase+7

  __shared__ int   id_s[NFP];
  __shared__ __align__(16) float val_s[NFP];
  __shared__ __align__(16) float w_s[NFP];
  __shared__ __align__(16) float rv_s[EH];
  __shared__ __align__(16) float u_s[EH];
  __shared__ __align__(16) float enc_s[EH];   // att[0:64] | qt[64:128]
  __shared__ __align__(16) float t1_s[SHD];
  __shared__ __align__(16) float sh_s[SD];
  __shared__ __align__(16) float a1_s[SD];
  __shared__ __align__(16) float v1_s[SD];

  // ---------------- phase 0: closed-form "argsort" (wave-local) -----------
  const int* __restrict__ arow = acquired + row * NF;
  #pragma unroll
  for (int j = 0; j < 4; ++j) { id_s[l + 64 * j] = 0; val_s[l + 64 * j] = 0.f; }
  if (l < 8) { id_s[NF + l] = 0; val_s[NF + l] = 0.f; w_s[NF + l] = 0.f; }
  int aiv[4];
  unsigned long long m0, m1, m2, m3;
  aiv[0] = (arow[l]       != 0); m0 = __ballot(aiv[0]);
  aiv[1] = (arow[64 + l]  != 0); m1 = __ballot(aiv[1]);
  aiv[2] = (arow[128 + l] != 0); m2 = __ballot(aiv[2]);
  aiv[3] = (arow[192 + l] != 0); m3 = __ballot(aiv[3]);
  const int pc0 = __popcll(m0), pc1 = __popcll(m1);
  const int pc2 = __popcll(m2), pc3 = __popcll(m3);
  const int L = pc0 + pc1 + pc2 + pc3;
  {  // rank = # acquired with index > tok (descending stable order)
    const int suf1 = pc1 + pc2 + pc3, suf2 = pc2 + pc3, suf3 = pc3;
    if (aiv[0]) { const int r = (int)__popcll((m0 >> l) >> 1) + suf1;
      id_s[r] = l + 1;       val_s[r] = state[row * NF + l]; }
    if (aiv[1]) { const int r = (int)__popcll((m1 >> l) >> 1) + suf2;
      id_s[r] = 64 + l + 1;  val_s[r] = state[row * NF + 64 + l]; }
    if (aiv[2]) { const int r = (int)__popcll((m2 >> l) >> 1) + suf3;
      id_s[r] = 128 + l + 1; val_s[r] = state[row * NF + 128 + l]; }
    if (aiv[3]) { const int r = (int)__popcll((m3 >> l) >> 1);
      id_s[r] = 192 + l + 1; val_s[r] = state[row * NF + 192 + l]; }
  }

  float ct_r = 0.f;

  // hoisted per-lane h-recompute constants for k-slice [kbase, kbase+8)
  const float4 z0 = *(const float4*)(We1 + kbase);        // row 0 (val weight)
  const float4 z1 = *(const float4*)(We1 + kbase + 4);
  const float4 c0 = *(const float4*)(be1 + kbase);
  const float4 c1 = *(const float4*)(be1 + kbase + 4);

  if (L > 0) {
    const float invL = 1.f / (float)L;
    // group g owns tokens {4i+g}; pairs (8j+g, 8j+4+g); trips balanced
    const int ntok  = (L > g) ? ((L - g + 3) >> 2) : 0;
    const int npair = (ntok + 1) >> 1;
    for (int it = 0; it < NSHUF; ++it) {
      if (it == 0) {
        // qt == 0 -> uniform softmax over first L tokens
        #pragma unroll
        for (int j = 0; j < 4; ++j) w_s[l + 64 * j] = (l + 64 * j < L) ? invL : 0.f;
      } else {
        // rv = We2 @ qt : lane computes rv[l], rv[64+l]; qt from LDS float4
        {
          const float4* __restrict__ r0 = (const float4*)(We2 + l * E);
          const float4* __restrict__ r1 = (const float4*)(We2 + (64 + l) * E);
          float a0 = 0.f, a1 = 0.f, b0 = 0.f, b1 = 0.f;
          #pragma unroll
          for (int j = 0; j < 16; j += 2) {
            const float4 x0 = r0[j], x1 = r1[j];
            const float4 q4 = *(const float4*)(enc_s + 64 + 4 * j);
            a0 = fmaf(x0.x, q4.x, a0); a1 = fmaf(x1.x, q4.x, a1);
            a0 = fmaf(x0.y, q4.y, a0); a1 = fmaf(x1.y, q4.y, a1);
            a0 = fmaf(x0.z, q4.z, a0); a1 = fmaf(x1.z, q4.z, a1);
            a0 = fmaf(x0.w, q4.w, a0); a1 = fmaf(x1.w, q4.w, a1);
            const float4 y0 = r0[j + 1], y1 = r1[j + 1];
            const float4 q5 = *(const float4*)(enc_s + 64 + 4 * j + 4);
            b0 = fmaf(y0.x, q5.x, b0); b1 = fmaf(y1.x, q5.x, b1);
            b0 = fmaf(y0.y, q5.y, b0); b1 = fmaf(y1.y, q5.y, b1);
            b0 = fmaf(y0.z, q5.z, b0); b1 = fmaf(y1.z, q5.z, b1);
            b0 = fmaf(y0.w, q5.w, b0); b1 = fmaf(y1.w, q5.w, b1);
          }
          rv_s[l] = a0 + b0; rv_s[64 + l] = a1 + b1;
        }
        const float4 ra = *(const float4*)(rv_s + kbase);
        const float4 rb = *(const float4*)(rv_s + kbase + 4);
        // logits: dual-stream + 1-deep prefetch software pipeline
        int tA = g, tB = g + 4;
        int   idA = id_s[tA]; float vA = val_s[tA];
        int   idB = id_s[tB]; float vB = val_s[tB];
        float4 gaA = *(const float4*)(We1 + idA * EH + kbase);
        float4 gbA = *(const float4*)(We1 + idA * EH + kbase + 4);
        float4 gaB = *(const float4*)(We1 + idB * EH + kbase);
        float4 gbB = *(const float4*)(We1 + idB * EH + kbase + 4);
        for (int j = 0; j < npair; ++j) {
          // prefetch pair j+1 (pad-safe: arrays sized NFP, w=0 beyond L)
          const int tA2 = tA + 8, tB2 = tB + 8;
          const int   idA2 = id_s[tA2]; const float vA2 = val_s[tA2];
          const int   idB2 = id_s[tB2]; const float vB2 = val_s[tB2];
          const float4 gaA2 = *(const float4*)(We1 + idA2 * EH + kbase);
          const float4 gbA2 = *(const float4*)(We1 + idA2 * EH + kbase + 4);
          const float4 gaB2 = *(const float4*)(We1 + idB2 * EH + kbase);
          const float4 gbB2 = *(const float4*)(We1 + idB2 * EH + kbase + 4);
          // compute pair j
          float h, p, q;
          h = fmaxf(fmaf(vA, z0.x, gaA.x) + c0.x, 0.f); p = h * ra.x;
          h = fmaxf(fmaf(vA, z0.y, gaA.y) + c0.y, 0.f); p = fmaf(h, ra.y, p);
          h = fmaxf(fmaf(vA, z0.z, gaA.z) + c0.z, 0.f); p = fmaf(h, ra.z, p);
          h = fmaxf(fmaf(vA, z0.w, gaA.w) + c0.w, 0.f); p = fmaf(h, ra.w, p);
          h = fmaxf(fmaf(vA, z1.x, gbA.x) + c1.x, 0.f); p = fmaf(h, rb.x, p);
          h = fmaxf(fmaf(vA, z1.y, gbA.y) + c1.y, 0.f); p = fmaf(h, rb.y, p);
          h = fmaxf(fmaf(vA, z1.z, gbA.z) + c1.z, 0.f); p = fmaf(h, rb.z, p);
          h = fmaxf(fmaf(vA, z1.w, gbA.w) + c1.w, 0.f); p = fmaf(h, rb.w, p);
          h = fmaxf(fmaf(vB, z0.x, gaB.x) + c0.x, 0.f); q = h * ra.x;
          h = fmaxf(fmaf(vB, z0.y, gaB.y) + c0.y, 0.f); q = fmaf(h, ra.y, q);
          h = fmaxf(fmaf(vB, z0.z, gaB.z) + c0.z, 0.f); q = fmaf(h, ra.z, q);
          h = fmaxf(fmaf(vB, z0.w, gaB.w) + c0.w, 0.f); q = fmaf(h, ra.w, q);
          h = fmaxf(fmaf(vB, z1.x, gbB.x) + c1.x, 0.f); q = fmaf(h, rb.x, q);
          h = fmaxf(fmaf(vB, z1.y, gbB.y) + c1.y, 0.f); q = fmaf(h, rb.y, q);
          h = fmaxf(fmaf(vB, z1.z, gbB.z) + c1.z, 0.f); q = fmaf(h, rb.z, q);
          h = fmaxf(fmaf(vB, z1.w, gbB.w) + c1.w, 0.f); q = fmaf(h, rb.w, q);
          p += __shfl_xor(p, 1); q += __shfl_xor(q, 1);
          p += __shfl_xor(p, 2); q += __shfl_xor(q, 2);
          p += __shfl_xor(p, 4); q += __shfl_xor(q, 4);
          p += __shfl_xor(p, 8); q += __shfl_xor(q, 8);
          if (sub == 0) { w_s[tA] = p; w_s[tB] = q; }
          // rotate pipeline
          tA = tA2; tB = tB2; idA = idA2; vA = vA2; idB = idB2; vB = vB2;
          gaA = gaA2; gbA = gbA2; gaB = gaB2; gbB = gbB2;
        }
        // softmax over w_s[0..L), 4 tokens per lane
        float x0 = (l < L)       ? w_s[l]       : -1e30f;
        float x1 = (64 + l < L)  ? w_s[64 + l]  : -1e30f;
        float x2 = (128 + l < L) ? w_s[128 + l] : -1e30f;
        float x3 = (192 + l < L) ? w_s[192 + l] : -1e30f;
        float mx = fmaxf(fmaxf(x0, x1), fmaxf(x2, x3));
        #pragma unroll
        for (int d = 32; d > 0; d >>= 1) mx = fmaxf(mx, __shfl_xor(mx, d));
        const float e0 = (l < L)       ? __expf(x0 - mx) : 0.f;
        const float e1 = (64 + l < L)  ? __expf(x1 - mx) : 0.f;
        const float e2 = (128 + l < L) ? __expf(x2 - mx) : 0.f;
        const float e3 = (192 + l < L) ? __expf(x3 - mx) : 0.f;
        float s = (e0 + e1) + (e2 + e3);
        #pragma unroll
        for (int d = 32; d > 0; d >>= 1) s += __shfl_xor(s, d);
        const float inv = 1.f / s;
        w_s[l]       = e0 * inv;
        w_s[64 + l]  = e1 * inv;
        w_s[128 + l] = e2 * inv;
        w_s[192 + l] = e3 * inv;
      }

      // u[k] = sum_tok w*h : dual-stream + 1-deep prefetch pipeline
      float4 ua{0, 0, 0, 0}, ub{0, 0, 0, 0};
      {
        int tA = g, tB = g + 4;
        int   idA = id_s[tA]; float vA = val_s[tA]; float wA = w_s[tA];
        int   idB = id_s[tB]; float vB = val_s[tB]; float wB = w_s[tB];
        float4 gaA = *(const float4*)(We1 + idA * EH + kbase);
        float4 gbA = *(const float4*)(We1 + idA * EH + kbase + 4);
        float4 gaB = *(const float4*)(We1 + idB * EH + kbase);
        float4 gbB = *(const float4*)(We1 + idB * EH + kbase + 4);
        for (int j = 0; j < npair; ++j) {
          const int tA2 = tA + 8, tB2 = tB + 8;
          const int   idA2 = id_s[tA2]; const float vA2 = val_s[tA2];
          const float wA2 = w_s[tA2];
          const int   idB2 = id_s[tB2]; const float vB2 = val_s[tB2];
          const float wB2 = w_s[tB2];
          const float4 gaA2 = *(const float4*)(We1 + idA2 * EH + kbase);
          const float4 gbA2 = *(const float4*)(We1 + idA2 * EH + kbase + 4);
          const float4 gaB2 = *(const float4*)(We1 + idB2 * EH + kbase);
          const float4 gbB2 = *(const float4*)(We1 + idB2 * EH + kbase + 4);
          float h;
          h = fmaxf(fmaf(vA, z0.x, gaA.x) + c0.x, 0.f); ua.x = fmaf(wA, h, ua.x);
          h = fmaxf(fmaf(vA, z0.y, gaA.y) + c0.y, 0.f); ua.y = fmaf(wA, h, ua.y);
          h = fmaxf(fmaf(vA, z0.z, gaA.z) + c0.z, 0.f); ua.z = fmaf(wA, h, ua.z);
          h = fmaxf(fmaf(vA, z0.w, gaA.w) + c0.w, 0.f); ua.w = fmaf(wA, h, ua.w);
          h = fmaxf(fmaf(vA, z1.x, gbA.x) + c1.x, 0.f); ub.x = fmaf(wA, h, ub.x);
          h = fmaxf(fmaf(vA, z1.y, gbA.y) + c1.y, 0.f); ub.y = fmaf(wA, h, ub.y);
          h = fmaxf(fmaf(vA, z1.z, gbA.z) + c1.z, 0.f); ub.z = fmaf(wA, h, ub.z);
          h = fmaxf(fmaf(vA, z1.w, gbA.w) + c1.w, 0.f); ub.w = fmaf(wA, h, ub.w);
          h = fmaxf(fmaf(vB, z0.x, gaB.x) + c0.x, 0.f); ua.x = fmaf(wB, h, ua.x);
          h = fmaxf(fmaf(vB, z0.y, gaB.y) + c0.y, 0.f); ua.y = fmaf(wB, h, ua.y);
          h = fmaxf(fmaf(vB, z0.z, gaB.z) + c0.z, 0.f); ua.z = fmaf(wB, h, ua.z);
          h = fmaxf(fmaf(vB, z0.w, gaB.w) + c0.w, 0.f); ua.w = fmaf(wB, h, ua.w);
          h = fmaxf(fmaf(vB, z1.x, gbB.x) + c1.x, 0.f); ub.x = fmaf(wB, h, ub.x);
          h = fmaxf(fmaf(vB, z1.y, gbB.y) + c1.y, 0.f); ub.y = fmaf(wB, h, ub.y);
          h = fmaxf(fmaf(vB, z1.z, gbB.z) + c1.z, 0.f); ub.z = fmaf(wB, h, ub.z);
          h = fmaxf(fmaf(vB, z1.w, gbB.w) + c1.w, 0.f); ub.w = fmaf(wB, h, ub.w);
          tA = tA2; tB = tB2;
          idA = idA2; vA = vA2; wA = wA2;
          idB = idB2; vB = vB2; wB = wB2;
          gaA = gaA2; gbA = gbA2; gaB = gaB2; gbB = gbB2;
        }
      }
      #pragma unroll
      for (int d = 16; d <= 32; d <<= 1) {   // cross-group: same sub = same k
        ua.x += __shfl_xor(ua.x, d); ua.y += __shfl_xor(ua.y, d);
        ua.z += __shfl_xor(ua.z, d); ua.w += __shfl_xor(ua.w, d);
        ub.x += __shfl_xor(ub.x, d); ub.y += __shfl_xor(ub.y, d);
        ub.z += __shfl_xor(ub.z, d); ub.w += __shfl_xor(ub.w, d);
      }
      if (l < 16) {
        *(float4*)(u_s + l * 8)     = ua;
        *(float4*)(u_s + l * 8 + 4) = ub;
      }

      // attended[l] = sum_k u[k]*We2[k][l] + be2[l]   (coalesced columns)
      {
        float a0 = 0.f, a1 = 0.f, a2 = 0.f, a3 = 0.f;
        #pragma unroll 4
        for (int k = 0; k < EH; k += 4) {
          a0 = fmaf(u_s[k],     We2[(k)     * E + l], a0);
          a1 = fmaf(u_s[k + 1], We2[(k + 1) * E + l], a1);
          a2 = fmaf(u_s[k + 2], We2[(k + 2) * E + l], a2);
          a3 = fmaf(u_s[k + 3], We2[(k + 3) * E + l], a3);
        }
        enc_s[l] = (a0 + a1) + (a2 + a3) + be2[l];
      }

      // gates: lane l owns cells l -> cols l, 64+l, 128+l, 192+l (i,f,g,o)
      float gi = 0.f, gf = 0.f, gg = 0.f, go = 0.f;
      #pragma unroll 2
      for (int e = 0; e < E; ++e) {
        const float av = enc_s[e];
        const float* __restrict__ wc = Wih + e * 256;
        gi = fmaf(av, wc[l],       gi);
        gf = fmaf(av, wc[64 + l],  gf);
        gg = fmaf(av, wc[128 + l], gg);
        go = fmaf(av, wc[192 + l], go);
      }
      if (it > 0) {
        #pragma unroll 2
        for (int e = 0; e < E; ++e) {
          const float qv = enc_s[64 + e];
          const float* __restrict__ wc = Whh + e * 256;
          gi = fmaf(qv, wc[l],       gi);
          gf = fmaf(qv, wc[64 + l],  gf);
          gg = fmaf(qv, wc[128 + l], gg);
          go = fmaf(qv, wc[192 + l], go);
        }
      }
      gi += bih[l]       + bhh[l];
      gf += bih[64 + l]  + bhh[64 + l];
      gg += bih[128 + l] + bhh[128 + l];
      go += bih[192 + l] + bhh[192 + l];
      ct_r = fsig(gf) * ct_r + fsig(gi) * ftanh(gg);
      enc_s[64 + l] = fsig(go) * ftanh(ct_r);   // qt in LDS (wave-local)
    }
  } else {
    enc_s[l] = 0.f; enc_s[64 + l] = 0.f;   // reference zeroes encoded
  }

  // ---------------- phase 3: DuelingNet (wave-local, coalesced) -----------
  {  // t1 = relu(enc @ Ws1 + bs1): 4 cols per lane
    float t0 = 0.f, t1 = 0.f, t2 = 0.f, t3 = 0.f;
    #pragma unroll 2
    for (int k = 0; k < EH; ++k) {
      const float ev = enc_s[k];
      const float* __restrict__ wr = Ws1 + k * SHD;
      t0 = fmaf(ev, wr[l],       t0);
      t1 = fmaf(ev, wr[64 + l],  t1);
      t2 = fmaf(ev, wr[128 + l], t2);
      t3 = fmaf(ev, wr[192 + l], t3);
    }
    t1_s[l]       = fmaxf(t0 + bs1[l],       0.f);
    t1_s[64 + l]  = fmaxf(t1 + bs1[64 + l],  0.f);
    t1_s[128 + l] = fmaxf(t2 + bs1[128 + l], 0.f);
    t1_s[192 + l] = fmaxf(t3 + bs1[192 + l], 0.f);
  }
  {  // sh = relu(t1 @ Ws2 + bs2): 2 cols per lane
    float s0 = 0.f, s1 = 0.f;
    #pragma unroll 2
    for (int k = 0; k < SHD; ++k) {
      const float tv = t1_s[k];
      s0 = fmaf(tv, Ws2[k * SD + l],      s0);
      s1 = fmaf(tv, Ws2[k * SD + 64 + l], s1);
    }
    sh_s[l]      = fmaxf(s0 + bs2[l],      0.f);
    sh_s[64 + l] = fmaxf(s1 + bs2[64 + l], 0.f);
  }
  {  // a1 = relu(sh@Wp1+bp1), v1 = relu(sh@Wv1+bv1): 2 cols each per lane
    float p0 = 0.f, p1 = 0.f, q0 = 0.f, q1 = 0.f;
    #pragma unroll 2
    for (int k = 0; k < SD; ++k) {
      const float sv = sh_s[k];
      p0 = fmaf(sv, Wp1[k * SD + l],      p0);
      p1 = fmaf(sv, Wp1[k * SD + 64 + l], p1);
      q0 = fmaf(sv, Wv1[k * SD + l],      q0);
      q1 = fmaf(sv, Wv1[k * SD + 64 + l], q1);
    }
    a1_s[l]      = fmaxf(p0 + bp1[l],      0.f);
    a1_s[64 + l] = fmaxf(p1 + bp1[64 + l], 0.f);
    v1_s[l]      = fmaxf(q0 + bv1[l],      0.f);
    v1_s[64 + l] = fmaxf(q1 + bv1[64 + l], 0.f);
  }
  // adv cols l+64j (4 per lane)
  float a0 = 0.f, a1 = 0.f, a2 = 0.f, a3 = 0.f;
  #pragma unroll 2
  for (int k = 0; k < SD; ++k) {
    const float av = a1_s[k];
    const float* __restrict__ wr = Wp2 + k * NA;
    a0 = fmaf(av, wr[l],       a0);
    a1 = fmaf(av, wr[64 + l],  a1);
    a2 = fmaf(av, wr[128 + l], a2);
    a3 = fmaf(av, wr[192 + l], a3);
  }
  a0 += bp2[l]; a1 += bp2[64 + l]; a2 += bp2[128 + l]; a3 += bp2[192 + l];
  // adv col 256: distributed dot (2 k per lane) + butterfly
  float c4 = fmaf(a1_s[2 * l], Wp2[(2 * l) * NA + 256],
                  a1_s[2 * l + 1] * Wp2[(2 * l + 1) * NA + 256]);
  #pragma unroll
  for (int d = 32; d > 0; d >>= 1) c4 += __shfl_xor(c4, d);
  const float adv4 = c4 + bp2[256];
  // v scalar
  float vv = fmaf(v1_s[l], Wv2[l], v1_s[64 + l] * Wv2[64 + l]);
  #pragma unroll
  for (int d = 32; d > 0; d >>= 1) vv += __shfl_xor(vv, d);
  const float v = vv + bv2[0];
  // mean over 257 cols
  float ss = (a0 + a1) + (a2 + a3);
  #pragma unroll
  for (int d = 32; d > 0; d >>= 1) ss += __shfl_xor(ss, d);
  const float mean = (ss + adv4) * (1.f / (float)NA);

  const float base = v - mean;
  float* __restrict__ orow = out + row * NA;
  orow[l]       = base + a0;
  orow[64 + l]  = base + a1;
  orow[128 + l] = base + a2;
  orow[192 + l] = base + a3;
  if (l == 0) orow[256] = base + adv4;
}

}  // namespace

extern "C" void kernel_launch(void* const* d_in, const int* in_sizes, int n_in,
                              void* d_out, int out_size, void* d_ws, size_t ws_size,
                              hipStream_t stream) {
  const float* state    = (const float*)d_in[0];
  const int*   acquired = (const int*)d_in[1];
  const float* We1 = (const float*)d_in[2];
  const float* be1 = (const float*)d_in[3];
  const float* We2 = (const float*)d_in[4];
  const float* be2 = (const float*)d_in[5];
  const float* Wih = (const float*)d_in[6];
  const float* Whh = (const float*)d_in[7];
  const float* bih = (const float*)d_in[8];
  const float* bhh = (const float*)d_in[9];
  const float* Ws1 = (const float*)d_in[10];
  const float* bs1 = (const float*)d_in[11];
  const float* Ws2 = (const float*)d_in[12];
  const float* bs2 = (const float*)d_in[13];
  const float* Wp1 = (const float*)d_in[14];
  const float* bp1 = (const float*)d_in[15];
  const float* Wp2 = (const float*)d_in[16];
  const float* bp2 = (const float*)d_in[17];
  const float* Wv1 = (const float*)d_in[18];
  const float* bv1 = (const float*)d_in[19];
  const float* Wv2 = (const float*)d_in[20];
  const float* bv2 = (const float*)d_in[21];
  float* out = (float*)d_out;

  const int Bn = in_sizes[0] / NF;   // 2048 rows; one 64-thread wave per row
  hipLaunchKernelGGL(seqnet, dim3(Bn), dim3(64), 0, stream,
                     state, acquired, We1, be1, We2, be2, Wih, Whh, bih, bhh,
                     Ws1, bs1, Ws2, bs2, Wp1, bp1, Wp2, bp2, Wv1, bv1, Wv2, bv2,
                     out);
}

// Round 17
// 154.332 us; speedup vs baseline: 1.4123x; 1.0245x over previous
//
#include <hip/hip_runtime.h>
#include <math.h>

namespace {

constexpr int NF   = 256;    // n_feature / tokens
constexpr int NFP  = NF + 16;// padded (quad prefetch overrun, zero-filled)
constexpr int EH   = 128;    // embedder hidden
constexpr int E    = 64;     // embedded dim
constexpr int H    = 64;     // lstm size
constexpr int SHD  = 256;    // shared hidden
constexpr int SD   = 128;    // shared dim
constexpr int NA   = 257;    // n_action
constexpr int NSHUF = 4;

__device__ __forceinline__ float fsig(float x) {
  return 1.f / (1.f + __expf(-x));
}
__device__ __forceinline__ float ftanh(float x) {
  return 1.f - 2.f / (__expf(2.f * x) + 1.f);
}

// ONE WAVE PER ROW, ZERO BARRIERS (r14/r16 structure) + QUAD-STREAM token
// loops with 1-deep prefetch: 8 We1 rows in flight, ~128 cyc FMA per iter
// overlapping ~200 cyc L2 latency (r16 dual-stream hid only ~1/3).
// Factored attention (r11+ verified): logits = h.(We2 qt) (const cancels);
// attended = (sum w h)@We2 + be2; h recomputed from We1 on the fly.
__global__ __launch_bounds__(64)
void seqnet(
    const float* __restrict__ state, const int* __restrict__ acquired,
    const float* __restrict__ We1, const float* __restrict__ be1,
    const float* __restrict__ We2, const float* __restrict__ be2,
    const float* __restrict__ Wih, const float* __restrict__ Whh,
    const float* __restrict__ bih, const float* __restrict__ bhh,
    const float* __restrict__ Ws1, const float* __restrict__ bs1,
    const float* __restrict__ Ws2, const float* __restrict__ bs2,
    const float* __restrict__ Wp1, const float* __restrict__ bp1,
    const float* __restrict__ Wp2, const float* __restrict__ bp2,
    const float* __restrict__ Wv1, const float* __restrict__ bv1,
    const float* __restrict__ Wv2, const float* __restrict__ bv2,
    float* __restrict__ out)
{
  const int row = blockIdx.x;
  const int l   = threadIdx.x;    // 0..63 (one wave)
  const int g   = l >> 4;         // token group 0..3
  const int sub = l & 15;         // k-slice owner within group
  const int kbase = sub * 8;      // owns k = kbase..kbase+7

  __shared__ int   id_s[NFP];
  __shared__ __align__(16) float val_s[NFP];
  __shared__ __align__(16) float w_s[NFP];
  __shared__ __align__(16) float rv_s[EH];
  __shared__ __align__(16) float u_s[EH];
  __shared__ __align__(16) float enc_s[EH];   // att[0:64] | qt[64:128]
  __shared__ __align__(16) float t1_s[SHD];
  __shared__ __align__(16) float sh_s[SD];
  __shared__ __align__(16) float a1_s[SD];
  __shared__ __align__(16) float v1_s[SD];

  // ---------------- phase 0: closed-form "argsort" (wave-local) -----------
  const int* __restrict__ arow = acquired + row * NF;
  #pragma unroll
  for (int j = 0; j < 4; ++j) { id_s[l + 64 * j] = 0; val_s[l + 64 * j] = 0.f; }
  if (l < 16) { id_s[NF + l] = 0; val_s[NF + l] = 0.f; w_s[NF + l] = 0.f; }
  int aiv[4];
  unsigned long long m0, m1, m2, m3;
  aiv[0] = (arow[l]       != 0); m0 = __ballot(aiv[0]);
  aiv[1] = (arow[64 + l]  != 0); m1 = __ballot(aiv[1]);
  aiv[2] = (arow[128 + l] != 0); m2 = __ballot(aiv[2]);
  aiv[3] = (arow[192 + l] != 0); m3 = __ballot(aiv[3]);
  const int pc0 = __popcll(m0), pc1 = __popcll(m1);
  const int pc2 = __popcll(m2), pc3 = __popcll(m3);
  const int L = pc0 + pc1 + pc2 + pc3;
  {  // rank = # acquired with index > tok (descending stable order)
    const int suf1 = pc1 + pc2 + pc3, suf2 = pc2 + pc3, suf3 = pc3;
    if (aiv[0]) { const int r = (int)__popcll((m0 >> l) >> 1) + suf1;
      id_s[r] = l + 1;       val_s[r] = state[row * NF + l]; }
    if (aiv[1]) { const int r = (int)__popcll((m1 >> l) >> 1) + suf2;
      id_s[r] = 64 + l + 1;  val_s[r] = state[row * NF + 64 + l]; }
    if (aiv[2]) { const int r = (int)__popcll((m2 >> l) >> 1) + suf3;
      id_s[r] = 128 + l + 1; val_s[r] = state[row * NF + 128 + l]; }
    if (aiv[3]) { const int r = (int)__popcll((m3 >> l) >> 1);
      id_s[r] = 192 + l + 1; val_s[r] = state[row * NF + 192 + l]; }
  }

  float ct_r = 0.f;

  // hoisted per-lane h-recompute constants for k-slice [kbase, kbase+8)
  const float4 z0 = *(const float4*)(We1 + kbase);        // row 0 (val weight)
  const float4 z1 = *(const float4*)(We1 + kbase + 4);
  const float4 c0 = *(const float4*)(be1 + kbase);
  const float4 c1 = *(const float4*)(be1 + kbase + 4);

  if (L > 0) {
    const float invL = 1.f / (float)L;
    // group g owns tokens {4i+g}; quad = tokens 16j+g+{0,4,8,12}
    const int ntok  = (L > g) ? ((L - g + 3) >> 2) : 0;
    const int nquad = (ntok + 3) >> 2;
    for (int it = 0; it < NSHUF; ++it) {
      if (it == 0) {
        // qt == 0 -> uniform softmax over first L tokens
        #pragma unroll
        for (int j = 0; j < 4; ++j) w_s[l + 64 * j] = (l + 64 * j < L) ? invL : 0.f;
      } else {
        // rv = We2 @ qt : lane computes rv[l], rv[64+l]; qt from LDS float4
        {
          const float4* __restrict__ r0 = (const float4*)(We2 + l * E);
          const float4* __restrict__ r1 = (const float4*)(We2 + (64 + l) * E);
          float a0 = 0.f, a1 = 0.f, b0 = 0.f, b1 = 0.f;
          #pragma unroll
          for (int j = 0; j < 16; j += 2) {
            const float4 x0 = r0[j], x1 = r1[j];
            const float4 q4 = *(const float4*)(enc_s + 64 + 4 * j);
            a0 = fmaf(x0.x, q4.x, a0); a1 = fmaf(x1.x, q4.x, a1);
            a0 = fmaf(x0.y, q4.y, a0); a1 = fmaf(x1.y, q4.y, a1);
            a0 = fmaf(x0.z, q4.z, a0); a1 = fmaf(x1.z, q4.z, a1);
            a0 = fmaf(x0.w, q4.w, a0); a1 = fmaf(x1.w, q4.w, a1);
            const float4 y0 = r0[j + 1], y1 = r1[j + 1];
            const float4 q5 = *(const float4*)(enc_s + 64 + 4 * j + 4);
            b0 = fmaf(y0.x, q5.x, b0); b1 = fmaf(y1.x, q5.x, b1);
            b0 = fmaf(y0.y, q5.y, b0); b1 = fmaf(y1.y, q5.y, b1);
            b0 = fmaf(y0.z, q5.z, b0); b1 = fmaf(y1.z, q5.z, b1);
            b0 = fmaf(y0.w, q5.w, b0); b1 = fmaf(y1.w, q5.w, b1);
          }
          rv_s[l] = a0 + b0; rv_s[64 + l] = a1 + b1;
        }
        const float4 ra = *(const float4*)(rv_s + kbase);
        const float4 rb = *(const float4*)(rv_s + kbase + 4);
        // logits: quad-stream + 1-deep prefetch software pipeline
        float vcur[4]; float4 gA[4], gB[4];
        #pragma unroll
        for (int s = 0; s < 4; ++s) {
          const int tk = g + 4 * s;
          const int idt = id_s[tk]; vcur[s] = val_s[tk];
          gA[s] = *(const float4*)(We1 + idt * EH + kbase);
          gB[s] = *(const float4*)(We1 + idt * EH + kbase + 4);
        }
        for (int j = 0; j < nquad; ++j) {
          const int bnext = 16 * (j + 1) + g;
          float vnxt[4]; float4 gA2[4], gB2[4];
          #pragma unroll
          for (int s = 0; s < 4; ++s) {   // prefetch (pad-safe to NFP)
            const int tk = bnext + 4 * s;
            const int idt = id_s[tk]; vnxt[s] = val_s[tk];
            gA2[s] = *(const float4*)(We1 + idt * EH + kbase);
            gB2[s] = *(const float4*)(We1 + idt * EH + kbase + 4);
          }
          float p[4];
          #pragma unroll
          for (int s = 0; s < 4; ++s) {
            float h, pp;
            h = fmaxf(fmaf(vcur[s], z0.x, gA[s].x) + c0.x, 0.f); pp = h * ra.x;
            h = fmaxf(fmaf(vcur[s], z0.y, gA[s].y) + c0.y, 0.f); pp = fmaf(h, ra.y, pp);
            h = fmaxf(fmaf(vcur[s], z0.z, gA[s].z) + c0.z, 0.f); pp = fmaf(h, ra.z, pp);
            h = fmaxf(fmaf(vcur[s], z0.w, gA[s].w) + c0.w, 0.f); pp = fmaf(h, ra.w, pp);
            h = fmaxf(fmaf(vcur[s], z1.x, gB[s].x) + c1.x, 0.f); pp = fmaf(h, rb.x, pp);
            h = fmaxf(fmaf(vcur[s], z1.y, gB[s].y) + c1.y, 0.f); pp = fmaf(h, rb.y, pp);
            h = fmaxf(fmaf(vcur[s], z1.z, gB[s].z) + c1.z, 0.f); pp = fmaf(h, rb.z, pp);
            h = fmaxf(fmaf(vcur[s], z1.w, gB[s].w) + c1.w, 0.f); pp = fmaf(h, rb.w, pp);
            p[s] = pp;
          }
          #pragma unroll
          for (int s = 0; s < 4; ++s) {
            p[s] += __shfl_xor(p[s], 1); p[s] += __shfl_xor(p[s], 2);
            p[s] += __shfl_xor(p[s], 4); p[s] += __shfl_xor(p[s], 8);
          }
          if (sub == 0) {
            const int bcur = 16 * j + g;
            w_s[bcur]      = p[0]; w_s[bcur + 4]  = p[1];
            w_s[bcur + 8]  = p[2]; w_s[bcur + 12] = p[3];
          }
          #pragma unroll
          for (int s = 0; s < 4; ++s) { vcur[s] = vnxt[s]; gA[s] = gA2[s]; gB[s] = gB2[s]; }
        }
        // softmax over w_s[0..L), 4 tokens per lane
        float x0 = (l < L)       ? w_s[l]       : -1e30f;
        float x1 = (64 + l < L)  ? w_s[64 + l]  : -1e30f;
        float x2 = (128 + l < L) ? w_s[128 + l] : -1e30f;
        float x3 = (192 + l < L) ? w_s[192 + l] : -1e30f;
        float mx = fmaxf(fmaxf(x0, x1), fmaxf(x2, x3));
        #pragma unroll
        for (int d = 32; d > 0; d >>= 1) mx = fmaxf(mx, __shfl_xor(mx, d));
        const float e0 = (l < L)       ? __expf(x0 - mx) : 0.f;
        const float e1 = (64 + l < L)  ? __expf(x1 - mx) : 0.f;
        const float e2 = (128 + l < L) ? __expf(x2 - mx) : 0.f;
        const float e3 = (192 + l < L) ? __expf(x3 - mx) : 0.f;
        float s = (e0 + e1) + (e2 + e3);
        #pragma unroll
        for (int d = 32; d > 0; d >>= 1) s += __shfl_xor(s, d);
        const float inv = 1.f / s;
        w_s[l]       = e0 * inv;
        w_s[64 + l]  = e1 * inv;
        w_s[128 + l] = e2 * inv;
        w_s[192 + l] = e3 * inv;
      }

      // u[k] = sum_tok w*h : quad-stream + 1-deep prefetch pipeline
      float4 ua{0, 0, 0, 0}, ub{0, 0, 0, 0};
      {
        float vcur[4], wcur[4]; float4 gA[4], gB[4];
        #pragma unroll
        for (int s = 0; s < 4; ++s) {
          const int tk = g + 4 * s;
          const int idt = id_s[tk]; vcur[s] = val_s[tk]; wcur[s] = w_s[tk];
          gA[s] = *(const float4*)(We1 + idt * EH + kbase);
          gB[s] = *(const float4*)(We1 + idt * EH + kbase + 4);
        }
        for (int j = 0; j < nquad; ++j) {
          const int bnext = 16 * (j + 1) + g;
          float vnxt[4], wnxt[4]; float4 gA2[4], gB2[4];
          #pragma unroll
          for (int s = 0; s < 4; ++s) {   // prefetch (pad-safe; w=0 beyond L)
            const int tk = bnext + 4 * s;
            const int idt = id_s[tk]; vnxt[s] = val_s[tk]; wnxt[s] = w_s[tk];
            gA2[s] = *(const float4*)(We1 + idt * EH + kbase);
            gB2[s] = *(const float4*)(We1 + idt * EH + kbase + 4);
          }
          #pragma unroll
          for (int s = 0; s < 4; ++s) {
            const float vt = vcur[s], wt = wcur[s];
            float h;
            h = fmaxf(fmaf(vt, z0.x, gA[s].x) + c0.x, 0.f); ua.x = fmaf(wt, h, ua.x);
            h = fmaxf(fmaf(vt, z0.y, gA[s].y) + c0.y, 0.f); ua.y = fmaf(wt, h, ua.y);
            h = fmaxf(fmaf(vt, z0.z, gA[s].z) + c0.z, 0.f); ua.z = fmaf(wt, h, ua.z);
            h = fmaxf(fmaf(vt, z0.w, gA[s].w) + c0.w, 0.f); ua.w = fmaf(wt, h, ua.w);
            h = fmaxf(fmaf(vt, z1.x, gB[s].x) + c1.x, 0.f); ub.x = fmaf(wt, h, ub.x);
            h = fmaxf(fmaf(vt, z1.y, gB[s].y) + c1.y, 0.f); ub.y = fmaf(wt, h, ub.y);
            h = fmaxf(fmaf(vt, z1.z, gB[s].z) + c1.z, 0.f); ub.z = fmaf(wt, h, ub.z);
            h = fmaxf(fmaf(vt, z1.w, gB[s].w) + c1.w, 0.f); ub.w = fmaf(wt, h, ub.w);
          }
          #pragma unroll
          for (int s = 0; s < 4; ++s) {
            vcur[s] = vnxt[s]; wcur[s] = wnxt[s]; gA[s] = gA2[s]; gB[s] = gB2[s];
          }
        }
      }
      #pragma unroll
      for (int d = 16; d <= 32; d <<= 1) {   // cross-group: same sub = same k
        ua.x += __shfl_xor(ua.x, d); ua.y += __shfl_xor(ua.y, d);
        ua.z += __shfl_xor(ua.z, d); ua.w += __shfl_xor(ua.w, d);
        ub.x += __shfl_xor(ub.x, d); ub.y += __shfl_xor(ub.y, d);
        ub.z += __shfl_xor(ub.z, d); ub.w += __shfl_xor(ub.w, d);
      }
      if (l < 16) {
        *(float4*)(u_s + l * 8)     = ua;
        *(float4*)(u_s + l * 8 + 4) = ub;
      }

      // attended[l] = sum_k u[k]*We2[k][l] + be2[l]   (coalesced columns)
      {
        float a0 = 0.f, a1 = 0.f, a2 = 0.f, a3 = 0.f;
        #pragma unroll 4
        for (int k = 0; k < EH; k += 4) {
          a0 = fmaf(u_s[k],     We2[(k)     * E + l], a0);
          a1 = fmaf(u_s[k + 1], We2[(k + 1) * E + l], a1);
          a2 = fmaf(u_s[k + 2], We2[(k + 2) * E + l], a2);
          a3 = fmaf(u_s[k + 3], We2[(k + 3) * E + l], a3);
        }
        enc_s[l] = (a0 + a1) + (a2 + a3) + be2[l];
      }

      // gates: lane l owns cells l -> cols l, 64+l, 128+l, 192+l (i,f,g,o)
      float gi = 0.f, gf = 0.f, gg = 0.f, go = 0.f;
      #pragma unroll 2
      for (int e = 0; e < E; ++e) {
        const float av = enc_s[e];
        const float* __restrict__ wc = Wih + e * 256;
        gi = fmaf(av, wc[l],       gi);
        gf = fmaf(av, wc[64 + l],  gf);
        gg = fmaf(av, wc[128 + l], gg);
        go = fmaf(av, wc[192 + l], go);
      }
      if (it > 0) {
        #pragma unroll 2
        for (int e = 0; e < E; ++e) {
          const float qv = enc_s[64 + e];
          const float* __restrict__ wc = Whh + e * 256;
          gi = fmaf(qv, wc[l],       gi);
          gf = fmaf(qv, wc[64 + l],  gf);
          gg = fmaf(qv, wc[128 + l], gg);
          go = fmaf(qv, wc[192 + l], go);
        }
      }
      gi += bih[l]       + bhh[l];
      gf += bih[64 + l]  + bhh[64 + l];
      gg += bih[128 + l] + bhh[128 + l];
      go += bih[192 + l] + bhh[192 + l];
      ct_r = fsig(gf) * ct_r + fsig(gi) * ftanh(gg);
      enc_s[64 + l] = fsig(go) * ftanh(ct_r);   // qt in LDS (wave-local)
    }
  } else {
    enc_s[l] = 0.f; enc_s[64 + l] = 0.f;   // reference zeroes encoded
  }

  // ---------------- phase 3: DuelingNet (wave-local, coalesced) -----------
  {  // t1 = relu(enc @ Ws1 + bs1): 4 cols per lane
    float t0 = 0.f, t1 = 0.f, t2 = 0.f, t3 = 0.f;
    #pragma unroll 2
    for (int k = 0; k < EH; ++k) {
      const float ev = enc_s[k];
      const float* __restrict__ wr = Ws1 + k * SHD;
      t0 = fmaf(ev, wr[l],       t0);
      t1 = fmaf(ev, wr[64 + l],  t1);
      t2 = fmaf(ev, wr[128 + l], t2);
      t3 = fmaf(ev, wr[192 + l], t3);
    }
    t1_s[l]       = fmaxf(t0 + bs1[l],       0.f);
    t1_s[64 + l]  = fmaxf(t1 + bs1[64 + l],  0.f);
    t1_s[128 + l] = fmaxf(t2 + bs1[128 + l], 0.f);
    t1_s[192 + l] = fmaxf(t3 + bs1[192 + l], 0.f);
  }
  {  // sh = relu(t1 @ Ws2 + bs2): 2 cols per lane
    float s0 = 0.f, s1 = 0.f;
    #pragma unroll 2
    for (int k = 0; k < SHD; ++k) {
      const float tv = t1_s[k];
      s0 = fmaf(tv, Ws2[k * SD + l],      s0);
      s1 = fmaf(tv, Ws2[k * SD + 64 + l], s1);
    }
    sh_s[l]      = fmaxf(s0 + bs2[l],      0.f);
    sh_s[64 + l] = fmaxf(s1 + bs2[64 + l], 0.f);
  }
  {  // a1 = relu(sh@Wp1+bp1), v1 = relu(sh@Wv1+bv1): 2 cols each per lane
    float p0 = 0.f, p1 = 0.f, q0 = 0.f, q1 = 0.f;
    #pragma unroll 2
    for (int k = 0; k < SD; ++k) {
      const float sv = sh_s[k];
      p0 = fmaf(sv, Wp1[k * SD + l],      p0);
      p1 = fmaf(sv, Wp1[k * SD + 64 + l], p1);
      q0 = fmaf(sv, Wv1[k * SD + l],      q0);
      q1 = fmaf(sv, Wv1[k * SD + 64 + l], q1);
    }
    a1_s[l]      = fmaxf(p0 + bp1[l],      0.f);
    a1_s[64 + l] = fmaxf(p1 + bp1[64 + l], 0.f);
    v1_s[l]      = fmaxf(q0 + bv1[l],      0.f);
    v1_s[64 + l] = fmaxf(q1 + bv1[64 + l], 0.f);
  }
  // adv cols l+64j (4 per lane)
  float a0 = 0.f, a1 = 0.f, a2 = 0.f, a3 = 0.f;
  #pragma unroll 2
  for (int k = 0; k < SD; ++k) {
    const float av = a1_s[k];
    const float* __restrict__ wr = Wp2 + k * NA;
    a0 = fmaf(av, wr[l],       a0);
    a1 = fmaf(av, wr[64 + l],  a1);
    a2 = fmaf(av, wr[128 + l], a2);
    a3 = fmaf(av, wr[192 + l], a3);
  }
  a0 += bp2[l]; a1 += bp2[64 + l]; a2 += bp2[128 + l]; a3 += bp2[192 + l];
  // adv col 256: distributed dot (2 k per lane) + butterfly
  float c4 = fmaf(a1_s[2 * l], Wp2[(2 * l) * NA + 256],
                  a1_s[2 * l + 1] * Wp2[(2 * l + 1) * NA + 256]);
  #pragma unroll
  for (int d = 32; d > 0; d >>= 1) c4 += __shfl_xor(c4, d);
  const float adv4 = c4 + bp2[256];
  // v scalar
  float vv = fmaf(v1_s[l], Wv2[l], v1_s[64 + l] * Wv2[64 + l]);
  #pragma unroll
  for (int d = 32; d > 0; d >>= 1) vv += __shfl_xor(vv, d);
  const float v = vv + bv2[0];
  // mean over 257 cols
  float ss = (a0 + a1) + (a2 + a3);
  #pragma unroll
  for (int d = 32; d > 0; d >>= 1) ss += __shfl_xor(ss, d);
  const float mean = (ss + adv4) * (1.f / (float)NA);

  const float base = v - mean;
  float* __restrict__ orow = out + row * NA;
  orow[l]       = base + a0;
  orow[64 + l]  = base + a1;
  orow[128 + l] = base + a2;
  orow[192 + l] = base + a3;
  if (l == 0) orow[256] = base + adv4;
}

}  // namespace

extern "C" void kernel_launch(void* const* d_in, const int* in_sizes, int n_in,
                              void* d_out, int out_size, void* d_ws, size_t ws_size,
                              hipStream_t stream) {
  const float* state    = (const float*)d_in[0];
  const int*   acquired = (const int*)d_in[1];
  const float* We1 = (const float*)d_in[2];
  const float* be1 = (const float*)d_in[3];
  const float* We2 = (const float*)d_in[4];
  const float* be2 = (const float*)d_in[5];
  const float* Wih = (const float*)d_in[6];
  const float* Whh = (const float*)d_in[7];
  const float* bih = (const float*)d_in[8];
  const float* bhh = (const float*)d_in[9];
  const float* Ws1 = (const float*)d_in[10];
  const float* bs1 = (const float*)d_in[11];
  const float* Ws2 = (const float*)d_in[12];
  const float* bs2 = (const float*)d_in[13];
  const float* Wp1 = (const float*)d_in[14];
  const float* bp1 = (const float*)d_in[15];
  const float* Wp2 = (const float*)d_in[16];
  const float* bp2 = (const float*)d_in[17];
  const float* Wv1 = (const float*)d_in[18];
  const float* bv1 = (const float*)d_in[19];
  const float* Wv2 = (const float*)d_in[20];
  const float* bv2 = (const float*)d_in[21];
  float* out = (float*)d_out;

  const int Bn = in_sizes[0] / NF;   // 2048 rows; one 64-thread wave per row
  hipLaunchKernelGGL(seqnet, dim3(Bn), dim3(64), 0, stream,
                     state, acquired, We1, be1, We2, be2, Wih, Whh, bih, bhh,
                     Ws1, bs1, Ws2, bs2, Wp1, bp1, Wp2, bp2, Wv1, bv1, Wv2, bv2,
                     out);
}

// Round 18
// 153.691 us; speedup vs baseline: 1.4182x; 1.0042x over previous
//
#include <hip/hip_runtime.h>
#include <math.h>

namespace {

constexpr int NF   = 256;    // n_feature / tokens
constexpr int NFP  = NF + 16;// padded (quad prefetch overrun, zero-filled)
constexpr int EH   = 128;    // embedder hidden
constexpr int E    = 64;     // embedded dim
constexpr int H    = 64;     // lstm size
constexpr int SHD  = 256;    // shared hidden
constexpr int SD   = 128;    // shared dim
constexpr int NA   = 257;    // n_action
constexpr int NSHUF = 4;

__device__ __forceinline__ float fsig(float x) {
  return 1.f / (1.f + __expf(-x));
}
__device__ __forceinline__ float ftanh(float x) {
  return 1.f - 2.f / (__expf(2.f * x) + 1.f);
}

// ONE WAVE PER ROW, ZERO BARRIERS (r14/r16 structure) + QUAD-STREAM token
// loops with 1-deep prefetch: 8 We1 rows in flight, ~128 cyc FMA per iter
// overlapping ~200 cyc L2 latency (r16 dual-stream hid only ~1/3).
// Factored attention (r11+ verified): logits = h.(We2 qt) (const cancels);
// attended = (sum w h)@We2 + be2; h recomputed from We1 on the fly.
__global__ __launch_bounds__(64)
void seqnet(
    const float* __restrict__ state, const int* __restrict__ acquired,
    const float* __restrict__ We1, const float* __restrict__ be1,
    const float* __restrict__ We2, const float* __restrict__ be2,
    const float* __restrict__ Wih, const float* __restrict__ Whh,
    const float* __restrict__ bih, const float* __restrict__ bhh,
    const float* __restrict__ Ws1, const float* __restrict__ bs1,
    const float* __restrict__ Ws2, const float* __restrict__ bs2,
    const float* __restrict__ Wp1, const float* __restrict__ bp1,
    const float* __restrict__ Wp2, const float* __restrict__ bp2,
    const float* __restrict__ Wv1, const float* __restrict__ bv1,
    const float* __restrict__ Wv2, const float* __restrict__ bv2,
    float* __restrict__ out)
{
  const int row = blockIdx.x;
  const int l   = threadIdx.x;    // 0..63 (one wave)
  const int g   = l >> 4;         // token group 0..3
  const int sub = l & 15;         // k-slice owner within group
  const int kbase = sub * 8;      // owns k = kbase..kbase+7

  __shared__ int   id_s[NFP];
  __shared__ __align__(16) float val_s[NFP];
  __shared__ __align__(16) float w_s[NFP];
  __shared__ __align__(16) float rv_s[EH];
  __shared__ __align__(16) float u_s[EH];
  __shared__ __align__(16) float enc_s[EH];   // att[0:64] | qt[64:128]
  __shared__ __align__(16) float t1_s[SHD];
  __shared__ __align__(16) float sh_s[SD];
  __shared__ __align__(16) float a1_s[SD];
  __shared__ __align__(16) float v1_s[SD];

  // ---------------- phase 0: closed-form "argsort" (wave-local) -----------
  const int* __restrict__ arow = acquired + row * NF;
  #pragma unroll
  for (int j = 0; j < 4; ++j) { id_s[l + 64 * j] = 0; val_s[l + 64 * j] = 0.f; }
  if (l < 16) { id_s[NF + l] = 0; val_s[NF + l] = 0.f; w_s[NF + l] = 0.f; }
  int aiv[4];
  unsigned long long m0, m1, m2, m3;
  aiv[0] = (arow[l]       != 0); m0 = __ballot(aiv[0]);
  aiv[1] = (arow[64 + l]  != 0); m1 = __ballot(aiv[1]);
  aiv[2] = (arow[128 + l] != 0); m2 = __ballot(aiv[2]);
  aiv[3] = (arow[192 + l] != 0); m3 = __ballot(aiv[3]);
  const int pc0 = __popcll(m0), pc1 = __popcll(m1);
  const int pc2 = __popcll(m2), pc3 = __popcll(m3);
  const int L = pc0 + pc1 + pc2 + pc3;
  {  // rank = # acquired with index > tok (descending stable order)
    const int suf1 = pc1 + pc2 + pc3, suf2 = pc2 + pc3, suf3 = pc3;
    if (aiv[0]) { const int r = (int)__popcll((m0 >> l) >> 1) + suf1;
      id_s[r] = l + 1;       val_s[r] = state[row * NF + l]; }
    if (aiv[1]) { const int r = (int)__popcll((m1 >> l) >> 1) + suf2;
      id_s[r] = 64 + l + 1;  val_s[r] = state[row * NF + 64 + l]; }
    if (aiv[2]) { const int r = (int)__popcll((m2 >> l) >> 1) + suf3;
      id_s[r] = 128 + l + 1; val_s[r] = state[row * NF + 128 + l]; }
    if (aiv[3]) { const int r = (int)__popcll((m3 >> l) >> 1);
      id_s[r] = 192 + l + 1; val_s[r] = state[row * NF + 192 + l]; }
  }

  float ct_r = 0.f;

  // hoisted per-lane h-recompute constants for k-slice [kbase, kbase+8)
  const float4 z0 = *(const float4*)(We1 + kbase);        // row 0 (val weight)
  const float4 z1 = *(const float4*)(We1 + kbase + 4);
  const float4 c0 = *(const float4*)(be1 + kbase);
  const float4 c1 = *(const float4*)(be1 + kbase + 4);

  if (L > 0) {
    const float invL = 1.f / (float)L;
    // group g owns tokens {4i+g}; quad = tokens 16j+g+{0,4,8,12}
    const int ntok  = (L > g) ? ((L - g + 3) >> 2) : 0;
    const int nquad = (ntok + 3) >> 2;
    for (int it = 0; it < NSHUF; ++it) {
      if (it == 0) {
        // qt == 0 -> uniform softmax over first L tokens
        #pragma unroll
        for (int j = 0; j < 4; ++j) w_s[l + 64 * j] = (l + 64 * j < L) ? invL : 0.f;
      } else {
        // rv = We2 @ qt : lane computes rv[l], rv[64+l]; qt from LDS float4
        {
          const float4* __restrict__ r0 = (const float4*)(We2 + l * E);
          const float4* __restrict__ r1 = (const float4*)(We2 + (64 + l) * E);
          float a0 = 0.f, a1 = 0.f, b0 = 0.f, b1 = 0.f;
          #pragma unroll
          for (int j = 0; j < 16; j += 2) {
            const float4 x0 = r0[j], x1 = r1[j];
            const float4 q4 = *(const float4*)(enc_s + 64 + 4 * j);
            a0 = fmaf(x0.x, q4.x, a0); a1 = fmaf(x1.x, q4.x, a1);
            a0 = fmaf(x0.y, q4.y, a0); a1 = fmaf(x1.y, q4.y, a1);
            a0 = fmaf(x0.z, q4.z, a0); a1 = fmaf(x1.z, q4.z, a1);
            a0 = fmaf(x0.w, q4.w, a0); a1 = fmaf(x1.w, q4.w, a1);
            const float4 y0 = r0[j + 1], y1 = r1[j + 1];
            const float4 q5 = *(const float4*)(enc_s + 64 + 4 * j + 4);
            b0 = fmaf(y0.x, q5.x, b0); b1 = fmaf(y1.x, q5.x, b1);
            b0 = fmaf(y0.y, q5.y, b0); b1 = fmaf(y1.y, q5.y, b1);
            b0 = fmaf(y0.z, q5.z, b0); b1 = fmaf(y1.z, q5.z, b1);
            b0 = fmaf(y0.w, q5.w, b0); b1 = fmaf(y1.w, q5.w, b1);
          }
          rv_s[l] = a0 + b0; rv_s[64 + l] = a1 + b1;
        }
        const float4 ra = *(const float4*)(rv_s + kbase);
        const float4 rb = *(const float4*)(rv_s + kbase + 4);
        // logits: quad-stream + 1-deep prefetch software pipeline
        float vcur[4]; float4 gA[4], gB[4];
        #pragma unroll
        for (int s = 0; s < 4; ++s) {
          const int tk = g + 4 * s;
          const int idt = id_s[tk]; vcur[s] = val_s[tk];
          gA[s] = *(const float4*)(We1 + idt * EH + kbase);
          gB[s] = *(const float4*)(We1 + idt * EH + kbase + 4);
        }
        for (int j = 0; j < nquad; ++j) {
          const int bnext = 16 * (j + 1) + g;
          float vnxt[4]; float4 gA2[4], gB2[4];
          #pragma unroll
          for (int s = 0; s < 4; ++s) {   // prefetch (pad-safe to NFP)
            const int tk = bnext + 4 * s;
            const int idt = id_s[tk]; vnxt[s] = val_s[tk];
            gA2[s] = *(const float4*)(We1 + idt * EH + kbase);
            gB2[s] = *(const float4*)(We1 + idt * EH + kbase + 4);
          }
          float p[4];
          #pragma unroll
          for (int s = 0; s < 4; ++s) {
            float h, pp;
            h = fmaxf(fmaf(vcur[s], z0.x, gA[s].x) + c0.x, 0.f); pp = h * ra.x;
            h = fmaxf(fmaf(vcur[s], z0.y, gA[s].y) + c0.y, 0.f); pp = fmaf(h, ra.y, pp);
            h = fmaxf(fmaf(vcur[s], z0.z, gA[s].z) + c0.z, 0.f); pp = fmaf(h, ra.z, pp);
            h = fmaxf(fmaf(vcur[s], z0.w, gA[s].w) + c0.w, 0.f); pp = fmaf(h, ra.w, pp);
            h = fmaxf(fmaf(vcur[s], z1.x, gB[s].x) + c1.x, 0.f); pp = fmaf(h, rb.x, pp);
            h = fmaxf(fmaf(vcur[s], z1.y, gB[s].y) + c1.y, 0.f); pp = fmaf(h, rb.y, pp);
            h = fmaxf(fmaf(vcur[s], z1.z, gB[s].z) + c1.z, 0.f); pp = fmaf(h, rb.z, pp);
            h = fmaxf(fmaf(vcur[s], z1.w, gB[s].w) + c1.w, 0.f); pp = fmaf(h, rb.w, pp);
            p[s] = pp;
          }
          #pragma unroll
          for (int s = 0; s < 4; ++s) {
            p[s] += __shfl_xor(p[s], 1); p[s] += __shfl_xor(p[s], 2);
            p[s] += __shfl_xor(p[s], 4); p[s] += __shfl_xor(p[s], 8);
          }
          if (sub == 0) {
            const int bcur = 16 * j + g;
            w_s[bcur]      = p[0]; w_s[bcur + 4]  = p[1];
            w_s[bcur + 8]  = p[2]; w_s[bcur + 12] = p[3];
          }
          #pragma unroll
          for (int s = 0; s < 4; ++s) { vcur[s] = vnxt[s]; gA[s] = gA2[s]; gB[s] = gB2[s]; }
        }
        // softmax over w_s[0..L), 4 tokens per lane
        float x0 = (l < L)       ? w_s[l]       : -1e30f;
        float x1 = (64 + l < L)  ? w_s[64 + l]  : -1e30f;
        float x2 = (128 + l < L) ? w_s[128 + l] : -1e30f;
        float x3 = (192 + l < L) ? w_s[192 + l] : -1e30f;
        float mx = fmaxf(fmaxf(x0, x1), fmaxf(x2, x3));
        #pragma unroll
        for (int d = 32; d > 0; d >>= 1) mx = fmaxf(mx, __shfl_xor(mx, d));
        const float e0 = (l < L)       ? __expf(x0 - mx) : 0.f;
        const float e1 = (64 + l < L)  ? __expf(x1 - mx) : 0.f;
        const float e2 = (128 + l < L) ? __expf(x2 - mx) : 0.f;
        const float e3 = (192 + l < L) ? __expf(x3 - mx) : 0.f;
        float s = (e0 + e1) + (e2 + e3);
        #pragma unroll
        for (int d = 32; d > 0; d >>= 1) s += __shfl_xor(s, d);
        const float inv = 1.f / s;
        w_s[l]       = e0 * inv;
        w_s[64 + l]  = e1 * inv;
        w_s[128 + l] = e2 * inv;
        w_s[192 + l] = e3 * inv;
      }

      // u[k] = sum_tok w*h : quad-stream + 1-deep prefetch pipeline
      float4 ua{0, 0, 0, 0}, ub{0, 0, 0, 0};
      {
        float vcur[4], wcur[4]; float4 gA[4], gB[4];
        #pragma unroll
        for (int s = 0; s < 4; ++s) {
          const int tk = g + 4 * s;
          const int idt = id_s[tk]; vcur[s] = val_s[tk]; wcur[s] = w_s[tk];
          gA[s] = *(const float4*)(We1 + idt * EH + kbase);
          gB[s] = *(const float4*)(We1 + idt * EH + kbase + 4);
        }
        for (int j = 0; j < nquad; ++j) {
          const int bnext = 16 * (j + 1) + g;
          float vnxt[4], wnxt[4]; float4 gA2[4], gB2[4];
          #pragma unroll
          for (int s = 0; s < 4; ++s) {   // prefetch (pad-safe; w=0 beyond L)
            const int tk = bnext + 4 * s;
            const int idt = id_s[tk]; vnxt[s] = val_s[tk]; wnxt[s] = w_s[tk];
            gA2[s] = *(const float4*)(We1 + idt * EH + kbase);
            gB2[s] = *(const float4*)(We1 + idt * EH + kbase + 4);
          }
          #pragma unroll
          for (int s = 0; s < 4; ++s) {
            const float vt = vcur[s], wt = wcur[s];
            float h;
            h = fmaxf(fmaf(vt, z0.x, gA[s].x) + c0.x, 0.f); ua.x = fmaf(wt, h, ua.x);
            h = fmaxf(fmaf(vt, z0.y, gA[s].y) + c0.y, 0.f); ua.y = fmaf(wt, h, ua.y);
            h = fmaxf(fmaf(vt, z0.z, gA[s].z) + c0.z, 0.f); ua.z = fmaf(wt, h, ua.z);
            h = fmaxf(fmaf(vt, z0.w, gA[s].w) + c0.w, 0.f); ua.w = fmaf(wt, h, ua.w);
            h = fmaxf(fmaf(vt, z1.x, gB[s].x) + c1.x, 0.f); ub.x = fmaf(wt, h, ub.x);
            h = fmaxf(fmaf(vt, z1.y, gB[s].y) + c1.y, 0.f); ub.y = fmaf(wt, h, ub.y);
            h = fmaxf(fmaf(vt, z1.z, gB[s].z) + c1.z, 0.f); ub.z = fmaf(wt, h, ub.z);
            h = fmaxf(fmaf(vt, z1.w, gB[s].w) + c1.w, 0.f); ub.w = fmaf(wt, h, ub.w);
          }
          #pragma unroll
          for (int s = 0; s < 4; ++s) {
            vcur[s] = vnxt[s]; wcur[s] = wnxt[s]; gA[s] = gA2[s]; gB[s] = gB2[s];
          }
        }
      }
      #pragma unroll
      for (int d = 16; d <= 32; d <<= 1) {   // cross-group: same sub = same k
        ua.x += __shfl_xor(ua.x, d); ua.y += __shfl_xor(ua.y, d);
        ua.z += __shfl_xor(ua.z, d); ua.w += __shfl_xor(ua.w, d);
        ub.x += __shfl_xor(ub.x, d); ub.y += __shfl_xor(ub.y, d);
        ub.z += __shfl_xor(ub.z, d); ub.w += __shfl_xor(ub.w, d);
      }
      if (l < 16) {
        *(float4*)(u_s + l * 8)     = ua;
        *(float4*)(u_s + l * 8 + 4) = ub;
      }

      // attended[l] = sum_k u[k]*We2[k][l] + be2[l]   (coalesced columns)
      {
        float a0 = 0.f, a1 = 0.f, a2 = 0.f, a3 = 0.f;
        #pragma unroll 4
        for (int k = 0; k < EH; k += 4) {
          a0 = fmaf(u_s[k],     We2[(k)     * E + l], a0);
          a1 = fmaf(u_s[k + 1], We2[(k + 1) * E + l], a1);
          a2 = fmaf(u_s[k + 2], We2[(k + 2) * E + l], a2);
          a3 = fmaf(u_s[k + 3], We2[(k + 3) * E + l], a3);
        }
        enc_s[l] = (a0 + a1) + (a2 + a3) + be2[l];
      }

      // gates: lane l owns cells l -> cols l, 64+l, 128+l, 192+l (i,f,g,o)
      float gi = 0.f, gf = 0.f, gg = 0.f, go = 0.f;
      #pragma unroll 2
      for (int e = 0; e < E; ++e) {
        const float av = enc_s[e];
        const float* __restrict__ wc = Wih + e * 256;
        gi = fmaf(av, wc[l],       gi);
        gf = fmaf(av, wc[64 + l],  gf);
        gg = fmaf(av, wc[128 + l], gg);
        go = fmaf(av, wc[192 + l], go);
      }
      if (it > 0) {
        #pragma unroll 2
        for (int e = 0; e < E; ++e) {
          const float qv = enc_s[64 + e];
          const float* __restrict__ wc = Whh + e * 256;
          gi = fmaf(qv, wc[l],       gi);
          gf = fmaf(qv, wc[64 + l],  gf);
          gg = fmaf(qv, wc[128 + l], gg);
          go = fmaf(qv, wc[192 + l], go);
        }
      }
      gi += bih[l]       + bhh[l];
      gf += bih[64 + l]  + bhh[64 + l];
      gg += bih[128 + l] + bhh[128 + l];
      go += bih[192 + l] + bhh[192 + l];
      ct_r = fsig(gf) * ct_r + fsig(gi) * ftanh(gg);
      enc_s[64 + l] = fsig(go) * ftanh(ct_r);   // qt in LDS (wave-local)
    }
  } else {
    enc_s[l] = 0.f; enc_s[64 + l] = 0.f;   // reference zeroes encoded
  }

  // ---------------- phase 3: DuelingNet (wave-local, coalesced) -----------
  {  // t1 = relu(enc @ Ws1 + bs1): 4 cols per lane
    float t0 = 0.f, t1 = 0.f, t2 = 0.f, t3 = 0.f;
    #pragma unroll 2
    for (int k = 0; k < EH; ++k) {
      const float ev = enc_s[k];
      const float* __restrict__ wr = Ws1 + k * SHD;
      t0 = fmaf(ev, wr[l],       t0);
      t1 = fmaf(ev, wr[64 + l],  t1);
      t2 = fmaf(ev, wr[128 + l], t2);
      t3 = fmaf(ev, wr[192 + l], t3);
    }
    t1_s[l]       = fmaxf(t0 + bs1[l],       0.f);
    t1_s[64 + l]  = fmaxf(t1 + bs1[64 + l],  0.f);
    t1_s[128 + l] = fmaxf(t2 + bs1[128 + l], 0.f);
    t1_s[192 + l] = fmaxf(t3 + bs1[192 + l], 0.f);
  }
  {  // sh = relu(t1 @ Ws2 + bs2): 2 cols per lane
    float s0 = 0.f, s1 = 0.f;
    #pragma unroll 2
    for (int k = 0; k < SHD; ++k) {
      const float tv = t1_s[k];
      s0 = fmaf(tv, Ws2[k * SD + l],      s0);
      s1 = fmaf(tv, Ws2[k * SD + 64 + l], s1);
    }
    sh_s[l]      = fmaxf(s0 + bs2[l],      0.f);
    sh_s[64 + l] = fmaxf(s1 + bs2[64 + l], 0.f);
  }
  {  // a1 = relu(sh@Wp1+bp1), v1 = relu(sh@Wv1+bv1): 2 cols each per lane
    float p0 = 0.f, p1 = 0.f, q0 = 0.f, q1 = 0.f;
    #pragma unroll 2
    for (int k = 0; k < SD; ++k) {
      const float sv = sh_s[k];
      p0 = fmaf(sv, Wp1[k * SD + l],      p0);
      p1 = fmaf(sv, Wp1[k * SD + 64 + l], p1);
      q0 = fmaf(sv, Wv1[k * SD + l],      q0);
      q1 = fmaf(sv, Wv1[k * SD + 64 + l], q1);
    }
    a1_s[l]      = fmaxf(p0 + bp1[l],      0.f);
    a1_s[64 + l] = fmaxf(p1 + bp1[64 + l], 0.f);
    v1_s[l]      = fmaxf(q0 + bv1[l],      0.f);
    v1_s[64 + l] = fmaxf(q1 + bv1[64 + l], 0.f);
  }
  // adv cols l+64j (4 per lane)
  float a0 = 0.f, a1 = 0.f, a2 = 0.f, a3 = 0.f;
  #pragma unroll 2
  for (int k = 0; k < SD; ++k) {
    const float av = a1_s[k];
    const float* __restrict__ wr = Wp2 + k * NA;
    a0 = fmaf(av, wr[l],       a0);
    a1 = fmaf(av, wr[64 + l],  a1);
    a2 = fmaf(av, wr[128 + l], a2);
    a3 = fmaf(av, wr[192 + l], a3);
  }
  a0 += bp2[l]; a1 += bp2[64 + l]; a2 += bp2[128 + l]; a3 += bp2[192 + l];
  // adv col 256: distributed dot (2 k per lane) + butterfly
  float c4 = fmaf(a1_s[2 * l], Wp2[(2 * l) * NA + 256],
                  a1_s[2 * l + 1] * Wp2[(2 * l + 1) * NA + 256]);
  #pragma unroll
  for (int d = 32; d > 0; d >>= 1) c4 += __shfl_xor(c4, d);
  const float adv4 = c4 + bp2[256];
  // v scalar
  float vv = fmaf(v1_s[l], Wv2[l], v1_s[64 + l] * Wv2[64 + l]);
  #pragma unroll
  for (int d = 32; d > 0; d >>= 1) vv += __shfl_xor(vv, d);
  const float v = vv + bv2[0];
  // mean over 257 cols
  float ss = (a0 + a1) + (a2 + a3);
  #pragma unroll
  for (int d = 32; d > 0; d >>= 1) ss += __shfl_xor(ss, d);
  const float mean = (ss + adv4) * (1.f / (float)NA);

  const float base = v - mean;
  float* __restrict__ orow = out + row * NA;
  orow[l]       = base + a0;
  orow[64 + l]  = base + a1;
  orow[128 + l] = base + a2;
  orow[192 + l] = base + a3;
  if (l == 0) orow[256] = base + adv4;
}

}  // namespace

extern "C" void kernel_launch(void* const* d_in, const int* in_sizes, int n_in,
                              void* d_out, int out_size, void* d_ws, size_t ws_size,
                              hipStream_t stream) {
  const float* state    = (const float*)d_in[0];
  const int*   acquired = (const int*)d_in[1];
  const float* We1 = (const float*)d_in[2];
  const float* be1 = (const float*)d_in[3];
  const float* We2 = (const float*)d_in[4];
  const float* be2 = (const float*)d_in[5];
  const float* Wih = (const float*)d_in[6];
  const float* Whh = (const float*)d_in[7];
  const float* bih = (const float*)d_in[8];
  const float* bhh = (const float*)d_in[9];
  const float* Ws1 = (const float*)d_in[10];
  const float* bs1 = (const float*)d_in[11];
  const float* Ws2 = (const float*)d_in[12];
  const float* bs2 = (const float*)d_in[13];
  const float* Wp1 = (const float*)d_in[14];
  const float* bp1 = (const float*)d_in[15];
  const float* Wp2 = (const float*)d_in[16];
  const float* bp2 = (const float*)d_in[17];
  const float* Wv1 = (const float*)d_in[18];
  const float* bv1 = (const float*)d_in[19];
  const float* Wv2 = (const float*)d_in[20];
  const float* bv2 = (const float*)d_in[21];
  float* out = (float*)d_out;

  const int Bn = in_sizes[0] / NF;   // 2048 rows; one 64-thread wave per row
  hipLaunchKernelGGL(seqnet, dim3(Bn), dim3(64), 0, stream,
                     state, acquired, We1, be1, We2, be2, Wih, Whh, bih, bhh,
                     Ws1, bs1, Ws2, bs2, Wp1, bp1, Wp2, bp2, Wv1, bv1, Wv2, bv2,
                     out);
}

// Round 19
// 142.347 us; speedup vs baseline: 1.5312x; 1.0797x over previous
//
#include <hip/hip_runtime.h>
#include <math.h>

namespace {

constexpr int NF   = 256;    // n_feature / tokens
constexpr int NFP  = NF + 16;// padded (quad prefetch overrun, zero-filled)
constexpr int EH   = 128;    // embedder hidden
constexpr int E    = 64;     // embedded dim
constexpr int H    = 64;     // lstm size
constexpr int SHD  = 256;    // shared hidden
constexpr int SD   = 128;    // shared dim
constexpr int NA   = 257;    // n_action
constexpr int NSHUF = 4;

__device__ __forceinline__ float fsig(float x) {
  return 1.f / (1.f + __expf(-x));
}
__device__ __forceinline__ float ftanh(float x) {
  return 1.f - 2.f / (__expf(2.f * x) + 1.f);
}

// ONE WAVE PER ROW, ZERO BARRIERS (r14/r16/r18) + quad-stream token loops +
// THIS ROUND: vectorized weight streams. Gates and phase-3 matvecs were ~4300
// scalar dword loads/wave (4x the needed instructions); lane now owns 4 (or 2)
// CONSECUTIVE output cols -> float4/float2 weight loads, with a same-wave LDS
// roundtrip to restore per-cell gate layout for the LSTM elementwise.
// Factored attention (r11+ verified): logits = h.(We2 qt) (const cancels);
// attended = (sum w h)@We2 + be2; h recomputed from We1 on the fly.
__global__ __launch_bounds__(64)
void seqnet(
    const float* __restrict__ state, const int* __restrict__ acquired,
    const float* __restrict__ We1, const float* __restrict__ be1,
    const float* __restrict__ We2, const float* __restrict__ be2,
    const float* __restrict__ Wih, const float* __restrict__ Whh,
    const float* __restrict__ bih, const float* __restrict__ bhh,
    const float* __restrict__ Ws1, const float* __restrict__ bs1,
    const float* __restrict__ Ws2, const float* __restrict__ bs2,
    const float* __restrict__ Wp1, const float* __restrict__ bp1,
    const float* __restrict__ Wp2, const float* __restrict__ bp2,
    const float* __restrict__ Wv1, const float* __restrict__ bv1,
    const float* __restrict__ Wv2, const float* __restrict__ bv2,
    float* __restrict__ out)
{
  const int row = blockIdx.x;
  const int l   = threadIdx.x;    // 0..63 (one wave)
  const int g   = l >> 4;         // token group 0..3
  const int sub = l & 15;         // k-slice owner within group
  const int kbase = sub * 8;      // owns k = kbase..kbase+7

  __shared__ int   id_s[NFP];
  __shared__ __align__(16) float val_s[NFP];
  __shared__ __align__(16) float w_s[NFP];
  __shared__ __align__(16) float rv_s[EH];
  __shared__ __align__(16) float u_s[EH];
  __shared__ __align__(16) float enc_s[EH];   // att[0:64] | qt[64:128]
  __shared__ __align__(16) float gates_s[256];
  __shared__ __align__(16) float t1_s[SHD];
  __shared__ __align__(16) float sh_s[SD];
  __shared__ __align__(16) float a1_s[SD];
  __shared__ __align__(16) float v1_s[SD];

  // ---------------- phase 0: closed-form "argsort" (wave-local) -----------
  const int* __restrict__ arow = acquired + row * NF;
  #pragma unroll
  for (int j = 0; j < 4; ++j) { id_s[l + 64 * j] = 0; val_s[l + 64 * j] = 0.f; }
  if (l < 16) { id_s[NF + l] = 0; val_s[NF + l] = 0.f; w_s[NF + l] = 0.f; }
  int aiv[4];
  unsigned long long m0, m1, m2, m3;
  aiv[0] = (arow[l]       != 0); m0 = __ballot(aiv[0]);
  aiv[1] = (arow[64 + l]  != 0); m1 = __ballot(aiv[1]);
  aiv[2] = (arow[128 + l] != 0); m2 = __ballot(aiv[2]);
  aiv[3] = (arow[192 + l] != 0); m3 = __ballot(aiv[3]);
  const int pc0 = __popcll(m0), pc1 = __popcll(m1);
  const int pc2 = __popcll(m2), pc3 = __popcll(m3);
  const int L = pc0 + pc1 + pc2 + pc3;
  {  // rank = # acquired with index > tok (descending stable order)
    const int suf1 = pc1 + pc2 + pc3, suf2 = pc2 + pc3, suf3 = pc3;
    if (aiv[0]) { const int r = (int)__popcll((m0 >> l) >> 1) + suf1;
      id_s[r] = l + 1;       val_s[r] = state[row * NF + l]; }
    if (aiv[1]) { const int r = (int)__popcll((m1 >> l) >> 1) + suf2;
      id_s[r] = 64 + l + 1;  val_s[r] = state[row * NF + 64 + l]; }
    if (aiv[2]) { const int r = (int)__popcll((m2 >> l) >> 1) + suf3;
      id_s[r] = 128 + l + 1; val_s[r] = state[row * NF + 128 + l]; }
    if (aiv[3]) { const int r = (int)__popcll((m3 >> l) >> 1);
      id_s[r] = 192 + l + 1; val_s[r] = state[row * NF + 192 + l]; }
  }

  float ct_r = 0.f;

  // hoisted per-lane h-recompute constants for k-slice [kbase, kbase+8)
  const float4 z0 = *(const float4*)(We1 + kbase);        // row 0 (val weight)
  const float4 z1 = *(const float4*)(We1 + kbase + 4);
  const float4 c0 = *(const float4*)(be1 + kbase);
  const float4 c1 = *(const float4*)(be1 + kbase + 4);

  if (L > 0) {
    const float invL = 1.f / (float)L;
    // group g owns tokens {4i+g}; quad = tokens 16j+g+{0,4,8,12}
    const int ntok  = (L > g) ? ((L - g + 3) >> 2) : 0;
    const int nquad = (ntok + 3) >> 2;
    for (int it = 0; it < NSHUF; ++it) {
      if (it == 0) {
        // qt == 0 -> uniform softmax over first L tokens
        #pragma unroll
        for (int j = 0; j < 4; ++j) w_s[l + 64 * j] = (l + 64 * j < L) ? invL : 0.f;
      } else {
        // rv = We2 @ qt : lane computes rv[l], rv[64+l]; qt from LDS float4
        {
          const float4* __restrict__ r0 = (const float4*)(We2 + l * E);
          const float4* __restrict__ r1 = (const float4*)(We2 + (64 + l) * E);
          float a0 = 0.f, a1 = 0.f, b0 = 0.f, b1 = 0.f;
          #pragma unroll
          for (int j = 0; j < 16; j += 2) {
            const float4 x0 = r0[j], x1 = r1[j];
            const float4 q4 = *(const float4*)(enc_s + 64 + 4 * j);
            a0 = fmaf(x0.x, q4.x, a0); a1 = fmaf(x1.x, q4.x, a1);
            a0 = fmaf(x0.y, q4.y, a0); a1 = fmaf(x1.y, q4.y, a1);
            a0 = fmaf(x0.z, q4.z, a0); a1 = fmaf(x1.z, q4.z, a1);
            a0 = fmaf(x0.w, q4.w, a0); a1 = fmaf(x1.w, q4.w, a1);
            const float4 y0 = r0[j + 1], y1 = r1[j + 1];
            const float4 q5 = *(const float4*)(enc_s + 64 + 4 * j + 4);
            b0 = fmaf(y0.x, q5.x, b0); b1 = fmaf(y1.x, q5.x, b1);
            b0 = fmaf(y0.y, q5.y, b0); b1 = fmaf(y1.y, q5.y, b1);
            b0 = fmaf(y0.z, q5.z, b0); b1 = fmaf(y1.z, q5.z, b1);
            b0 = fmaf(y0.w, q5.w, b0); b1 = fmaf(y1.w, q5.w, b1);
          }
          rv_s[l] = a0 + b0; rv_s[64 + l] = a1 + b1;
        }
        const float4 ra = *(const float4*)(rv_s + kbase);
        const float4 rb = *(const float4*)(rv_s + kbase + 4);
        // logits: quad-stream + 1-deep prefetch software pipeline
        float vcur[4]; float4 gA[4], gB[4];
        #pragma unroll
        for (int s = 0; s < 4; ++s) {
          const int tk = g + 4 * s;
          const int idt = id_s[tk]; vcur[s] = val_s[tk];
          gA[s] = *(const float4*)(We1 + idt * EH + kbase);
          gB[s] = *(const float4*)(We1 + idt * EH + kbase + 4);
        }
        for (int j = 0; j < nquad; ++j) {
          const int bnext = 16 * (j + 1) + g;
          float vnxt[4]; float4 gA2[4], gB2[4];
          #pragma unroll
          for (int s = 0; s < 4; ++s) {   // prefetch (pad-safe to NFP)
            const int tk = bnext + 4 * s;
            const int idt = id_s[tk]; vnxt[s] = val_s[tk];
            gA2[s] = *(const float4*)(We1 + idt * EH + kbase);
            gB2[s] = *(const float4*)(We1 + idt * EH + kbase + 4);
          }
          float p[4];
          #pragma unroll
          for (int s = 0; s < 4; ++s) {
            float h, pp;
            h = fmaxf(fmaf(vcur[s], z0.x, gA[s].x) + c0.x, 0.f); pp = h * ra.x;
            h = fmaxf(fmaf(vcur[s], z0.y, gA[s].y) + c0.y, 0.f); pp = fmaf(h, ra.y, pp);
            h = fmaxf(fmaf(vcur[s], z0.z, gA[s].z) + c0.z, 0.f); pp = fmaf(h, ra.z, pp);
            h = fmaxf(fmaf(vcur[s], z0.w, gA[s].w) + c0.w, 0.f); pp = fmaf(h, ra.w, pp);
            h = fmaxf(fmaf(vcur[s], z1.x, gB[s].x) + c1.x, 0.f); pp = fmaf(h, rb.x, pp);
            h = fmaxf(fmaf(vcur[s], z1.y, gB[s].y) + c1.y, 0.f); pp = fmaf(h, rb.y, pp);
            h = fmaxf(fmaf(vcur[s], z1.z, gB[s].z) + c1.z, 0.f); pp = fmaf(h, rb.z, pp);
            h = fmaxf(fmaf(vcur[s], z1.w, gB[s].w) + c1.w, 0.f); pp = fmaf(h, rb.w, pp);
            p[s] = pp;
          }
          #pragma unroll
          for (int s = 0; s < 4; ++s) {
            p[s] += __shfl_xor(p[s], 1); p[s] += __shfl_xor(p[s], 2);
            p[s] += __shfl_xor(p[s], 4); p[s] += __shfl_xor(p[s], 8);
          }
          if (sub == 0) {
            const int bcur = 16 * j + g;
            w_s[bcur]      = p[0]; w_s[bcur + 4]  = p[1];
            w_s[bcur + 8]  = p[2]; w_s[bcur + 12] = p[3];
          }
          #pragma unroll
          for (int s = 0; s < 4; ++s) { vcur[s] = vnxt[s]; gA[s] = gA2[s]; gB[s] = gB2[s]; }
        }
        // softmax over w_s[0..L), 4 tokens per lane
        float x0 = (l < L)       ? w_s[l]       : -1e30f;
        float x1 = (64 + l < L)  ? w_s[64 + l]  : -1e30f;
        float x2 = (128 + l < L) ? w_s[128 + l] : -1e30f;
        float x3 = (192 + l < L) ? w_s[192 + l] : -1e30f;
        float mx = fmaxf(fmaxf(x0, x1), fmaxf(x2, x3));
        #pragma unroll
        for (int d = 32; d > 0; d >>= 1) mx = fmaxf(mx, __shfl_xor(mx, d));
        const float e0 = (l < L)       ? __expf(x0 - mx) : 0.f;
        const float e1 = (64 + l < L)  ? __expf(x1 - mx) : 0.f;
        const float e2 = (128 + l < L) ? __expf(x2 - mx) : 0.f;
        const float e3 = (192 + l < L) ? __expf(x3 - mx) : 0.f;
        float s = (e0 + e1) + (e2 + e3);
        #pragma unroll
        for (int d = 32; d > 0; d >>= 1) s += __shfl_xor(s, d);
        const float inv = 1.f / s;
        w_s[l]       = e0 * inv;
        w_s[64 + l]  = e1 * inv;
        w_s[128 + l] = e2 * inv;
        w_s[192 + l] = e3 * inv;
      }

      // u[k] = sum_tok w*h : quad-stream + 1-deep prefetch pipeline
      float4 ua{0, 0, 0, 0}, ub{0, 0, 0, 0};
      {
        float vcur[4], wcur[4]; float4 gA[4], gB[4];
        #pragma unroll
        for (int s = 0; s < 4; ++s) {
          const int tk = g + 4 * s;
          const int idt = id_s[tk]; vcur[s] = val_s[tk]; wcur[s] = w_s[tk];
          gA[s] = *(const float4*)(We1 + idt * EH + kbase);
          gB[s] = *(const float4*)(We1 + idt * EH + kbase + 4);
        }
        for (int j = 0; j < nquad; ++j) {
          const int bnext = 16 * (j + 1) + g;
          float vnxt[4], wnxt[4]; float4 gA2[4], gB2[4];
          #pragma unroll
          for (int s = 0; s < 4; ++s) {   // prefetch (pad-safe; w=0 beyond L)
            const int tk = bnext + 4 * s;
            const int idt = id_s[tk]; vnxt[s] = val_s[tk]; wnxt[s] = w_s[tk];
            gA2[s] = *(const float4*)(We1 + idt * EH + kbase);
            gB2[s] = *(const float4*)(We1 + idt * EH + kbase + 4);
          }
          #pragma unroll
          for (int s = 0; s < 4; ++s) {
            const float vt = vcur[s], wt = wcur[s];
            float h;
            h = fmaxf(fmaf(vt, z0.x, gA[s].x) + c0.x, 0.f); ua.x = fmaf(wt, h, ua.x);
            h = fmaxf(fmaf(vt, z0.y, gA[s].y) + c0.y, 0.f); ua.y = fmaf(wt, h, ua.y);
            h = fmaxf(fmaf(vt, z0.z, gA[s].z) + c0.z, 0.f); ua.z = fmaf(wt, h, ua.z);
            h = fmaxf(fmaf(vt, z0.w, gA[s].w) + c0.w, 0.f); ua.w = fmaf(wt, h, ua.w);
            h = fmaxf(fmaf(vt, z1.x, gB[s].x) + c1.x, 0.f); ub.x = fmaf(wt, h, ub.x);
            h = fmaxf(fmaf(vt, z1.y, gB[s].y) + c1.y, 0.f); ub.y = fmaf(wt, h, ub.y);
            h = fmaxf(fmaf(vt, z1.z, gB[s].z) + c1.z, 0.f); ub.z = fmaf(wt, h, ub.z);
            h = fmaxf(fmaf(vt, z1.w, gB[s].w) + c1.w, 0.f); ub.w = fmaf(wt, h, ub.w);
          }
          #pragma unroll
          for (int s = 0; s < 4; ++s) {
            vcur[s] = vnxt[s]; wcur[s] = wnxt[s]; gA[s] = gA2[s]; gB[s] = gB2[s];
          }
        }
      }
      #pragma unroll
      for (int d = 16; d <= 32; d <<= 1) {   // cross-group: same sub = same k
        ua.x += __shfl_xor(ua.x, d); ua.y += __shfl_xor(ua.y, d);
        ua.z += __shfl_xor(ua.z, d); ua.w += __shfl_xor(ua.w, d);
        ub.x += __shfl_xor(ub.x, d); ub.y += __shfl_xor(ub.y, d);
        ub.z += __shfl_xor(ub.z, d); ub.w += __shfl_xor(ub.w, d);
      }
      if (l < 16) {
        *(float4*)(u_s + l * 8)     = ua;
        *(float4*)(u_s + l * 8 + 4) = ub;
      }

      // attended[l] = sum_k u[k]*We2[k][l] + be2[l]   (coalesced columns)
      {
        float a0 = 0.f, a1 = 0.f, a2 = 0.f, a3 = 0.f;
        #pragma unroll 4
        for (int k = 0; k < EH; k += 4) {
          a0 = fmaf(u_s[k],     We2[(k)     * E + l], a0);
          a1 = fmaf(u_s[k + 1], We2[(k + 1) * E + l], a1);
          a2 = fmaf(u_s[k + 2], We2[(k + 2) * E + l], a2);
          a3 = fmaf(u_s[k + 3], We2[(k + 3) * E + l], a3);
        }
        enc_s[l] = (a0 + a1) + (a2 + a3) + be2[l];
      }

      // gates: lane owns cols 4l..4l+3 -> float4 weight loads; LDS roundtrip
      {
        float4 acc0{0, 0, 0, 0}, acc1{0, 0, 0, 0};
        #pragma unroll 2
        for (int e = 0; e < E; e += 2) {
          const float av0 = enc_s[e], av1 = enc_s[e + 1];
          const float4 w0 = *(const float4*)(Wih + (e)     * 256 + 4 * l);
          const float4 w1 = *(const float4*)(Wih + (e + 1) * 256 + 4 * l);
          acc0.x = fmaf(av0, w0.x, acc0.x); acc0.y = fmaf(av0, w0.y, acc0.y);
          acc0.z = fmaf(av0, w0.z, acc0.z); acc0.w = fmaf(av0, w0.w, acc0.w);
          acc1.x = fmaf(av1, w1.x, acc1.x); acc1.y = fmaf(av1, w1.y, acc1.y);
          acc1.z = fmaf(av1, w1.z, acc1.z); acc1.w = fmaf(av1, w1.w, acc1.w);
        }
        if (it > 0) {
          #pragma unroll 2
          for (int e = 0; e < E; e += 2) {
            const float qv0 = enc_s[64 + e], qv1 = enc_s[64 + e + 1];
            const float4 w0 = *(const float4*)(Whh + (e)     * 256 + 4 * l);
            const float4 w1 = *(const float4*)(Whh + (e + 1) * 256 + 4 * l);
            acc0.x = fmaf(qv0, w0.x, acc0.x); acc0.y = fmaf(qv0, w0.y, acc0.y);
            acc0.z = fmaf(qv0, w0.z, acc0.z); acc0.w = fmaf(qv0, w0.w, acc0.w);
            acc1.x = fmaf(qv1, w1.x, acc1.x); acc1.y = fmaf(qv1, w1.y, acc1.y);
            acc1.z = fmaf(qv1, w1.z, acc1.z); acc1.w = fmaf(qv1, w1.w, acc1.w);
          }
        }
        const float4 bi = *(const float4*)(bih + 4 * l);
        const float4 bh = *(const float4*)(bhh + 4 * l);
        float4 gacc;
        gacc.x = acc0.x + acc1.x + bi.x + bh.x;
        gacc.y = acc0.y + acc1.y + bi.y + bh.y;
        gacc.z = acc0.z + acc1.z + bi.z + bh.z;
        gacc.w = acc0.w + acc1.w + bi.w + bh.w;
        *(float4*)(gates_s + 4 * l) = gacc;
        // per-cell gates back from LDS (same-wave RAW, ordered)
        const float gi = gates_s[l];
        const float gf = gates_s[64 + l];
        const float gg = gates_s[128 + l];
        const float go = gates_s[192 + l];
        ct_r = fsig(gf) * ct_r + fsig(gi) * ftanh(gg);
        enc_s[64 + l] = fsig(go) * ftanh(ct_r);   // qt in LDS (wave-local)
      }
    }
  } else {
    enc_s[l] = 0.f; enc_s[64 + l] = 0.f;   // reference zeroes encoded
  }

  // ---------------- phase 3: DuelingNet (vectorized weight streams) -------
  {  // t1 cols 4l..4l+3 via float4; dual-parity accumulators
    float4 acc0{0, 0, 0, 0}, acc1{0, 0, 0, 0};
    #pragma unroll 2
    for (int k = 0; k < EH; k += 2) {
      const float e0 = enc_s[k], e1 = enc_s[k + 1];
      const float4 w0 = *(const float4*)(Ws1 + (k)     * SHD + 4 * l);
      const float4 w1 = *(const float4*)(Ws1 + (k + 1) * SHD + 4 * l);
      acc0.x = fmaf(e0, w0.x, acc0.x); acc0.y = fmaf(e0, w0.y, acc0.y);
      acc0.z = fmaf(e0, w0.z, acc0.z); acc0.w = fmaf(e0, w0.w, acc0.w);
      acc1.x = fmaf(e1, w1.x, acc1.x); acc1.y = fmaf(e1, w1.y, acc1.y);
      acc1.z = fmaf(e1, w1.z, acc1.z); acc1.w = fmaf(e1, w1.w, acc1.w);
    }
    const float4 b4 = *(const float4*)(bs1 + 4 * l);
    t1_s[4 * l]     = fmaxf(acc0.x + acc1.x + b4.x, 0.f);
    t1_s[4 * l + 1] = fmaxf(acc0.y + acc1.y + b4.y, 0.f);
    t1_s[4 * l + 2] = fmaxf(acc0.z + acc1.z + b4.z, 0.f);
    t1_s[4 * l + 3] = fmaxf(acc0.w + acc1.w + b4.w, 0.f);
  }
  {  // sh cols 2l, 2l+1 via float2
    float2 acc0{0, 0}, acc1{0, 0};
    #pragma unroll 2
    for (int k = 0; k < SHD; k += 2) {
      const float t0 = t1_s[k], t1v = t1_s[k + 1];
      const float2 w0 = *(const float2*)(Ws2 + (k)     * SD + 2 * l);
      const float2 w1 = *(const float2*)(Ws2 + (k + 1) * SD + 2 * l);
      acc0.x = fmaf(t0, w0.x, acc0.x); acc0.y = fmaf(t0, w0.y, acc0.y);
      acc1.x = fmaf(t1v, w1.x, acc1.x); acc1.y = fmaf(t1v, w1.y, acc1.y);
    }
    sh_s[2 * l]     = fmaxf(acc0.x + acc1.x + bs2[2 * l],     0.f);
    sh_s[2 * l + 1] = fmaxf(acc0.y + acc1.y + bs2[2 * l + 1], 0.f);
  }
  {  // a1, v1 cols 2l, 2l+1 via float2 (two independent streams)
    float2 pa{0, 0}, qa{0, 0};
    #pragma unroll 2
    for (int k = 0; k < SD; ++k) {
      const float sv = sh_s[k];
      const float2 wp = *(const float2*)(Wp1 + k * SD + 2 * l);
      const float2 wv = *(const float2*)(Wv1 + k * SD + 2 * l);
      pa.x = fmaf(sv, wp.x, pa.x); pa.y = fmaf(sv, wp.y, pa.y);
      qa.x = fmaf(sv, wv.x, qa.x); qa.y = fmaf(sv, wv.y, qa.y);
    }
    a1_s[2 * l]     = fmaxf(pa.x + bp1[2 * l],     0.f);
    a1_s[2 * l + 1] = fmaxf(pa.y + bp1[2 * l + 1], 0.f);
    v1_s[2 * l]     = fmaxf(qa.x + bv1[2 * l],     0.f);
    v1_s[2 * l + 1] = fmaxf(qa.y + bv1[2 * l + 1], 0.f);
  }
  // adv cols l+64j (4 per lane; Wp2 row stride 257 -> keep coalesced dword)
  float a0 = 0.f, a1 = 0.f, a2 = 0.f, a3 = 0.f;
  #pragma unroll 2
  for (int k = 0; k < SD; ++k) {
    const float av = a1_s[k];
    const float* __restrict__ wr = Wp2 + k * NA;
    a0 = fmaf(av, wr[l],       a0);
    a1 = fmaf(av, wr[64 + l],  a1);
    a2 = fmaf(av, wr[128 + l], a2);
    a3 = fmaf(av, wr[192 + l], a3);
  }
  a0 += bp2[l]; a1 += bp2[64 + l]; a2 += bp2[128 + l]; a3 += bp2[192 + l];
  // adv col 256: distributed dot (2 k per lane) + butterfly
  float c4 = fmaf(a1_s[2 * l], Wp2[(2 * l) * NA + 256],
                  a1_s[2 * l + 1] * Wp2[(2 * l + 1) * NA + 256]);
  #pragma unroll
  for (int d = 32; d > 0; d >>= 1) c4 += __shfl_xor(c4, d);
  const float adv4 = c4 + bp2[256];
  // v scalar
  float vv = fmaf(v1_s[l], Wv2[l], v1_s[64 + l] * Wv2[64 + l]);
  #pragma unroll
  for (int d = 32; d > 0; d >>= 1) vv += __shfl_xor(vv, d);
  const float v = vv + bv2[0];
  // mean over 257 cols
  float ss = (a0 + a1) + (a2 + a3);
  #pragma unroll
  for (int d = 32; d > 0; d >>= 1) ss += __shfl_xor(ss, d);
  const float mean = (ss + adv4) * (1.f / (float)NA);

  const float base = v - mean;
  float* __restrict__ orow = out + row * NA;
  orow[l]       = base + a0;
  orow[64 + l]  = base + a1;
  orow[128 + l] = base + a2;
  orow[192 + l] = base + a3;
  if (l == 0) orow[256] = base + adv4;
}

}  // namespace

extern "C" void kernel_launch(void* const* d_in, const int* in_sizes, int n_in,
                              void* d_out, int out_size, void* d_ws, size_t ws_size,
                              hipStream_t stream) {
  const float* state    = (const float*)d_in[0];
  const int*   acquired = (const int*)d_in[1];
  const float* We1 = (const float*)d_in[2];
  const float* be1 = (const float*)d_in[3];
  const float* We2 = (const float*)d_in[4];
  const float* be2 = (const float*)d_in[5];
  const float* Wih = (const float*)d_in[6];
  const float* Whh = (const float*)d_in[7];
  const float* bih = (const float*)d_in[8];
  const float* bhh = (const float*)d_in[9];
  const float* Ws1 = (const float*)d_in[10];
  const float* bs1 = (const float*)d_in[11];
  const float* Ws2 = (const float*)d_in[12];
  const float* bs2 = (const float*)d_in[13];
  const float* Wp1 = (const float*)d_in[14];
  const float* bp1 = (const float*)d_in[15];
  const float* Wp2 = (const float*)d_in[16];
  const float* bp2 = (const float*)d_in[17];
  const float* Wv1 = (const float*)d_in[18];
  const float* bv1 = (const float*)d_in[19];
  const float* Wv2 = (const float*)d_in[20];
  const float* bv2 = (const float*)d_in[21];
  float* out = (float*)d_out;

  const int Bn = in_sizes[0] / NF;   // 2048 rows; one 64-thread wave per row
  hipLaunchKernelGGL(seqnet, dim3(Bn), dim3(64), 0, stream,
                     state, acquired, We1, be1, We2, be2, Wih, Whh, bih, bhh,
                     Ws1, bs1, Ws2, bs2, Wp1, bp1, Wp2, bp2, Wv1, bv1, Wv2, bv2,
                     out);
}